// Round 1
// baseline (1452.747 us; speedup 1.0000x reference)
//
#include <hip/hip_runtime.h>
#include <math.h>

#define BN_K 0.9999950000374997f  // 1/sqrt(1+1e-5)

static __device__ __forceinline__ float lrelu02(float x) { return x > 0.f ? x : 0.2f * x; }

// ---------------- tiny precompute: v0[4][16] = We0[:,h*64:+64] @ ae0[h]; v1[16] = We1 @ ae1 ----
__global__ void k_ae_vec(const float* __restrict__ We0, const float* __restrict__ ae0,
                         const float* __restrict__ We1, const float* __restrict__ ae1,
                         float* __restrict__ v0, float* __restrict__ v1)
{
    int t = threadIdx.x;
    if (t < 64) {
        int h = t >> 4, k = t & 15;
        float s = 0.f;
        for (int c = 0; c < 64; ++c) s += We0[k * 256 + h * 64 + c] * ae0[h * 64 + c];
        v0[h * 16 + k] = s;
    } else if (t < 80) {
        int k = t - 64;
        float s = 0.f;
        for (int c = 0; c < 32; ++c) s += We1[k * 32 + c] * ae1[c];
        v1[k] = s;
    }
}

// ---------------- self-loop edge_attr = scatter-mean over dst ----------------
__global__ void k_loop_acc(const float* __restrict__ ea, const int* __restrict__ dst,
                           float* __restrict__ esum, float* __restrict__ cnt, int E)
{
    int t = blockIdx.x * blockDim.x + threadIdx.x;
    if (t >= E * 16) return;
    int e = t >> 4, k = t & 15;
    int d = dst[e];
    atomicAdd(&esum[(size_t)d * 16 + k], ea[t]);
    if (k == 0) atomicAdd(&cnt[d], 1.f);
}

__global__ void k_loop_div(float* __restrict__ esum, const float* __restrict__ cnt, int N)
{
    int t = blockIdx.x * blockDim.x + threadIdx.x;
    if (t >= N * 16) return;
    int i = t >> 4;
    esum[t] = esum[t] / fmaxf(cnt[i], 1.f);
}

// ---------------- CSR build over dst (self-loops included: deg init = 1) ----------------
__global__ void k_deg_init(int* __restrict__ deg, int N)
{
    int i = blockIdx.x * blockDim.x + threadIdx.x;
    if (i < N) deg[i] = 1;
}

__global__ void k_deg_count(const int* __restrict__ dst, int* __restrict__ deg, int E)
{
    int e = blockIdx.x * blockDim.x + threadIdx.x;
    if (e < E) atomicAdd(&deg[dst[e]], 1);
}

__global__ __launch_bounds__(1024) void k_scan(const int* __restrict__ deg,
                                               int* __restrict__ rowptr,
                                               int* __restrict__ cur, int n)
{
    __shared__ int sbuf[1024];
    int t = threadIdx.x;
    int off = 0;
    for (int base = 0; base < n; base += 1024) {
        int i = base + t;
        int v = (i < n) ? deg[i] : 0;
        sbuf[t] = v;
        __syncthreads();
        for (int d = 1; d < 1024; d <<= 1) {
            int tmp = (t >= d) ? sbuf[t - d] : 0;
            __syncthreads();
            sbuf[t] += tmp;
            __syncthreads();
        }
        int inc = sbuf[t];
        if (i < n) { rowptr[i + 1] = off + inc; cur[i] = off + inc - v; }
        if (base == 0 && t == 0) rowptr[0] = 0;
        int tot = sbuf[1023];
        __syncthreads();
        off += tot;
    }
}

__global__ void k_fill(const int* __restrict__ dst, int* __restrict__ cur,
                       int* __restrict__ col, int E, int N)
{
    int t = blockIdx.x * blockDim.x + threadIdx.x;
    if (t >= E + N) return;
    int d = (t < E) ? dst[t] : (t - E);
    int slot = atomicAdd(&cur[d], 1);
    col[slot] = t;  // eid: t<E original edge; t=E+i self-loop of node i
}

// ---------------- generic fp32 GEMM: C = A[M,K] @ B[K,N] with epilogue ----------------
// mode 0: +bias ; mode 1: relu(+bias) ; mode 2: BN(relu(+bias))
__global__ __launch_bounds__(256) void k_gemm(const float* __restrict__ A,
                                              const float* __restrict__ B,
                                              float* __restrict__ C,
                                              int M, int Nc, int K,
                                              const float* __restrict__ bias, int mode,
                                              const float* __restrict__ g,
                                              const float* __restrict__ bb)
{
    __shared__ float As[16][68];
    __shared__ float Bs[16][68];
    int t = threadIdx.x;
    int tx = t & 15, ty = t >> 4;
    int row0 = blockIdx.x * 64, col0 = blockIdx.y * 64;
    float acc[4][4] = {};
    int r = t >> 2, kk4 = (t & 3) * 4;
    for (int k0 = 0; k0 < K; k0 += 16) {
        {
            int rg = row0 + r;
            float4 av = make_float4(0.f, 0.f, 0.f, 0.f);
            if (rg < M) av = *(const float4*)(A + (size_t)rg * K + k0 + kk4);
            As[kk4 + 0][r] = av.x; As[kk4 + 1][r] = av.y;
            As[kk4 + 2][r] = av.z; As[kk4 + 3][r] = av.w;
        }
        {
            int c = t & 63, kb = t >> 6;
            int cg = col0 + c;
#pragma unroll
            for (int q = 0; q < 4; ++q) {
                int k = kb + q * 4;
                Bs[k][c] = (cg < Nc) ? B[(size_t)(k0 + k) * Nc + cg] : 0.f;
            }
        }
        __syncthreads();
#pragma unroll
        for (int kk = 0; kk < 16; ++kk) {
            float4 a4 = *(const float4*)&As[kk][ty * 4];
            float4 b4 = *(const float4*)&Bs[kk][tx * 4];
            float a[4] = {a4.x, a4.y, a4.z, a4.w};
            float b[4] = {b4.x, b4.y, b4.z, b4.w};
#pragma unroll
            for (int i = 0; i < 4; ++i)
#pragma unroll
                for (int j = 0; j < 4; ++j) acc[i][j] = fmaf(a[i], b[j], acc[i][j]);
        }
        __syncthreads();
    }
#pragma unroll
    for (int i = 0; i < 4; ++i) {
        int row = row0 + ty * 4 + i;
        if (row >= M) continue;
#pragma unroll
        for (int j = 0; j < 4; ++j) {
            int colc = col0 + tx * 4 + j;
            if (colc >= Nc) continue;
            float v = acc[i][j] + (bias ? bias[colc] : 0.f);
            if (mode == 1) v = fmaxf(v, 0.f);
            else if (mode == 2) v = fmaxf(v, 0.f) * (BN_K * g[colc]) + bb[colc];
            C[(size_t)row * Nc + colc] = v;
        }
    }
}

// ---------------- attention source/dest dots, layer 0 (wave per node) ----------------
__global__ void k_attdots0(const float* __restrict__ xw, const float* __restrict__ as0,
                           const float* __restrict__ ad0, float* __restrict__ a_s,
                           float* __restrict__ a_d, int N)
{
    int wid = (blockIdx.x * blockDim.x + threadIdx.x) >> 6;
    int lane = threadIdx.x & 63;
    if (wid >= N) return;
    int h = lane >> 4, c4 = (lane & 15) * 4;
    float4 xv = *(const float4*)(xw + (size_t)wid * 256 + lane * 4);
    float4 sv = *(const float4*)(as0 + h * 64 + c4);
    float4 dv = *(const float4*)(ad0 + h * 64 + c4);
    float ps = xv.x * sv.x + xv.y * sv.y + xv.z * sv.z + xv.w * sv.w;
    float pd = xv.x * dv.x + xv.y * dv.y + xv.z * dv.z + xv.w * dv.w;
#pragma unroll
    for (int m = 1; m < 16; m <<= 1) { ps += __shfl_xor(ps, m); pd += __shfl_xor(pd, m); }
    if ((lane & 15) == 0) { a_s[(size_t)wid * 4 + h] = ps; a_d[(size_t)wid * 4 + h] = pd; }
}

__global__ void k_attdots1(const float* __restrict__ xw, const float* __restrict__ as1,
                           const float* __restrict__ ad1, float* __restrict__ a_s,
                           float* __restrict__ a_d, int N)
{
    int i = blockIdx.x * blockDim.x + threadIdx.x;
    if (i >= N) return;
    float s = 0.f, d = 0.f;
    for (int j = 0; j < 32; ++j) {
        float v = xw[(size_t)i * 32 + j];
        s = fmaf(v, as1[j], s);
        d = fmaf(v, ad1[j], d);
    }
    a_s[i] = s; a_d[i] = d;
}

// ---------------- per-edge attention-edge terms (original edges + self loops) ----------------
__global__ void k_edge_ae(const float* __restrict__ ea, const float* __restrict__ loop_attr,
                          const float* __restrict__ v0, const float* __restrict__ v1,
                          float* __restrict__ a_e0, float* __restrict__ a_e1, int E, int N)
{
    int idx = blockIdx.x * blockDim.x + threadIdx.x;
    if (idx >= E + N) return;
    const float* row = (idx < E) ? (ea + (size_t)idx * 16) : (loop_attr + (size_t)(idx - E) * 16);
    float r[16];
#pragma unroll
    for (int k = 0; k < 16; ++k) r[k] = row[k];
#pragma unroll
    for (int h = 0; h < 4; ++h) {
        float s = 0.f;
#pragma unroll
        for (int k = 0; k < 16; ++k) s = fmaf(r[k], v0[h * 16 + k], s);
        a_e0[(size_t)idx * 4 + h] = s;
    }
    float s1 = 0.f;
#pragma unroll
    for (int k = 0; k < 16; ++k) s1 = fmaf(r[k], v1[k], s1);
    a_e1[idx] = s1;
}

// ---------------- GAT layer 0 aggregation: wave per node, fused +b0 -> BN -> ELU ----------------
__global__ __launch_bounds__(64) void k_gat0_agg(
    const int* __restrict__ rowptr, const int* __restrict__ col, const int* __restrict__ srcA,
    const float* __restrict__ a_s, const float* __restrict__ a_d, const float* __restrict__ a_e,
    const float* __restrict__ xw, const float* __restrict__ b0,
    const float* __restrict__ bng, const float* __restrict__ bnb,
    float* __restrict__ hout, int N, int E)
{
    int i = blockIdx.x;
    int lane = threadIdx.x;
    int beg = rowptr[i], end = rowptr[i + 1];
    float ad[4];
#pragma unroll
    for (int h = 0; h < 4; ++h) ad[h] = a_d[(size_t)i * 4 + h];

    float mx[4] = {-1e30f, -1e30f, -1e30f, -1e30f};
    for (int p = beg + lane; p < end; p += 64) {
        int eid = col[p];
        int s = (eid < E) ? srcA[eid] : i;
        float4 as4 = *(const float4*)(a_s + (size_t)s * 4);
        float4 ae4 = *(const float4*)(a_e + (size_t)eid * 4);
        mx[0] = fmaxf(mx[0], lrelu02(as4.x + ad[0] + ae4.x));
        mx[1] = fmaxf(mx[1], lrelu02(as4.y + ad[1] + ae4.y));
        mx[2] = fmaxf(mx[2], lrelu02(as4.z + ad[2] + ae4.z));
        mx[3] = fmaxf(mx[3], lrelu02(as4.w + ad[3] + ae4.w));
    }
#pragma unroll
    for (int h = 0; h < 4; ++h)
#pragma unroll
        for (int m = 1; m < 64; m <<= 1) mx[h] = fmaxf(mx[h], __shfl_xor(mx[h], m));

    __shared__ float wls[256];
    int hl = lane >> 4;
    float accx = 0.f, accy = 0.f, accz = 0.f, accw = 0.f;
    float s0 = 0.f, s1 = 0.f, s2 = 0.f, s3 = 0.f;
    for (int base = beg; base < end; base += 64) {
        int p = base + lane;
        int cnt = min(64, end - base);
        if (p < end) {
            int eid = col[p];
            int s = (eid < E) ? srcA[eid] : i;
            float4 as4 = *(const float4*)(a_s + (size_t)s * 4);
            float4 ae4 = *(const float4*)(a_e + (size_t)eid * 4);
            float w0 = expf(lrelu02(as4.x + ad[0] + ae4.x) - mx[0]);
            float w1 = expf(lrelu02(as4.y + ad[1] + ae4.y) - mx[1]);
            float w2 = expf(lrelu02(as4.z + ad[2] + ae4.z) - mx[2]);
            float w3 = expf(lrelu02(as4.w + ad[3] + ae4.w) - mx[3]);
            s0 += w0; s1 += w1; s2 += w2; s3 += w3;
            wls[lane * 4 + 0] = w0; wls[lane * 4 + 1] = w1;
            wls[lane * 4 + 2] = w2; wls[lane * 4 + 3] = w3;
        }
        __syncthreads();
        for (int q = 0; q < cnt; ++q) {
            int eid = col[base + q];
            int s = (eid < E) ? srcA[eid] : i;
            float w = wls[q * 4 + hl];
            float4 xv = *(const float4*)(xw + (size_t)s * 256 + lane * 4);
            accx = fmaf(w, xv.x, accx);
            accy = fmaf(w, xv.y, accy);
            accz = fmaf(w, xv.z, accz);
            accw = fmaf(w, xv.w, accw);
        }
        __syncthreads();
    }
#pragma unroll
    for (int m = 1; m < 64; m <<= 1) {
        s0 += __shfl_xor(s0, m); s1 += __shfl_xor(s1, m);
        s2 += __shfl_xor(s2, m); s3 += __shfl_xor(s3, m);
    }
    float sden = ((hl == 0) ? s0 : (hl == 1) ? s1 : (hl == 2) ? s2 : s3) + 1e-16f;

    int ch = lane * 4;
    float out[4] = {accx / sden, accy / sden, accz / sden, accw / sden};
    float4 ov;
    float* po = (float*)&ov;
#pragma unroll
    for (int j = 0; j < 4; ++j) {
        int c = ch + j;
        float v = out[j] + b0[c];
        v = v * (BN_K * bng[c]) + bnb[c];
        po[j] = (v > 0.f) ? v : expm1f(v);
    }
    *(float4*)(hout + (size_t)i * 256 + ch) = ov;
}

// ---------------- GAT layer 1 aggregation: wave per node, fused +b1, writes z ----------------
__global__ __launch_bounds__(64) void k_gat1_agg(
    const int* __restrict__ rowptr, const int* __restrict__ col, const int* __restrict__ srcA,
    const float* __restrict__ a_s, const float* __restrict__ a_d, const float* __restrict__ a_e,
    const float* __restrict__ xw, const float* __restrict__ b1,
    float* __restrict__ zout, int N, int E)
{
    int i = blockIdx.x;
    int lane = threadIdx.x;
    int beg = rowptr[i], end = rowptr[i + 1];
    float ad = a_d[i];
    float mx = -1e30f;
    for (int p = beg + lane; p < end; p += 64) {
        int eid = col[p];
        int s = (eid < E) ? srcA[eid] : i;
        mx = fmaxf(mx, lrelu02(a_s[s] + ad + a_e[eid]));
    }
#pragma unroll
    for (int m = 1; m < 64; m <<= 1) mx = fmaxf(mx, __shfl_xor(mx, m));

    __shared__ float wls[64];
    float acc = 0.f, ssum = 0.f;
    for (int base = beg; base < end; base += 64) {
        int p = base + lane;
        int cnt = min(64, end - base);
        if (p < end) {
            int eid = col[p];
            int s = (eid < E) ? srcA[eid] : i;
            float w = expf(lrelu02(a_s[s] + ad + a_e[eid]) - mx);
            ssum += w;
            wls[lane] = w;
        }
        __syncthreads();
        if (lane < 32) {
            for (int q = 0; q < cnt; ++q) {
                int eid = col[base + q];
                int s = (eid < E) ? srcA[eid] : i;
                acc = fmaf(wls[q], xw[(size_t)s * 32 + lane], acc);
            }
        }
        __syncthreads();
    }
#pragma unroll
    for (int m = 1; m < 64; m <<= 1) ssum += __shfl_xor(ssum, m);
    if (lane < 32) zout[(size_t)i * 32 + lane] = acc / (ssum + 1e-16f) + b1[lane];
}

// ---------------- fused edge decoder: [z|zsrc,zdst,ea] -> 128 -> 64 -> 1 -> sigmoid ----------------
#define EDT 32
__global__ __launch_bounds__(256) void k_edge_dec(
    const float* __restrict__ z, const float* __restrict__ ea,
    const int* __restrict__ srcA, const int* __restrict__ dstA,
    const float* __restrict__ W1, const float* __restrict__ b1,
    const float* __restrict__ g1, const float* __restrict__ bb1,
    const float* __restrict__ W2, const float* __restrict__ b2,
    const float* __restrict__ W3, const float* __restrict__ b3v,
    float* __restrict__ out, int E)
{
    __shared__ float sW1[80][128];
    __shared__ float sW2[128][64];
    __shared__ float sW3[64];
    __shared__ float sb1[128], sg1[128], sbb1[128], sb2[64];
    __shared__ float s_ef[EDT][84];
    __shared__ float s_h1[EDT][132];
    __shared__ float s_h2[EDT][68];

    int t = threadIdx.x;
    for (int idx = t; idx < 80 * 128; idx += 256) sW1[idx / 128][idx % 128] = W1[idx];
    for (int idx = t; idx < 128 * 64; idx += 256) sW2[idx / 64][idx % 64] = W2[idx];
    if (t < 64) { sW3[t] = W3[t]; sb2[t] = b2[t]; }
    if (t < 128) { sb1[t] = b1[t]; sg1[t] = g1[t] * BN_K; sbb1[t] = bb1[t]; }
    float b3 = b3v[0];
    __syncthreads();

    int lane16 = t & 15;
    int epair = t >> 4;  // 0..15; handles edges epair and epair+16 of the tile

    for (int tile = blockIdx.x * EDT; tile < E; tile += gridDim.x * EDT) {
        {   // stage ef rows: 32 edges x 80 (zsrc|zdst|ea)
            int e_loc = t & 31;
            int part = t >> 5;  // 0..7
            int e = tile + e_loc;
            if (e < E) {
                int s = srcA[e], d = dstA[e];
                float4 zs = *(const float4*)(z + (size_t)s * 32 + part * 4);
                float4 zd = *(const float4*)(z + (size_t)d * 32 + part * 4);
                *(float4*)&s_ef[e_loc][part * 4] = zs;
                *(float4*)&s_ef[e_loc][32 + part * 4] = zd;
                if (part < 4)
                    *(float4*)&s_ef[e_loc][64 + part * 4] = *(const float4*)(ea + (size_t)e * 16 + part * 4);
            } else {
                float4 zz = make_float4(0.f, 0.f, 0.f, 0.f);
                *(float4*)&s_ef[e_loc][part * 4] = zz;
                *(float4*)&s_ef[e_loc][32 + part * 4] = zz;
                if (part < 4) *(float4*)&s_ef[e_loc][64 + part * 4] = zz;
            }
        }
        __syncthreads();

        // layer 1: h1 = BN(relu(ef @ W1 + b1)), each thread: 2 edges x 8 outputs
        {
            float acc[2][8] = {};
            for (int k = 0; k < 80; ++k) {
                float e0 = s_ef[epair][k];
                float e1 = s_ef[epair + 16][k];
                float4 wA = *(const float4*)&sW1[k][lane16 * 8];
                float4 wB = *(const float4*)&sW1[k][lane16 * 8 + 4];
                float w[8] = {wA.x, wA.y, wA.z, wA.w, wB.x, wB.y, wB.z, wB.w};
#pragma unroll
                for (int jj = 0; jj < 8; ++jj) {
                    acc[0][jj] = fmaf(e0, w[jj], acc[0][jj]);
                    acc[1][jj] = fmaf(e1, w[jj], acc[1][jj]);
                }
            }
#pragma unroll
            for (int jj = 0; jj < 8; ++jj) {
                int j = lane16 * 8 + jj;
                s_h1[epair][j]      = fmaxf(acc[0][jj] + sb1[j], 0.f) * sg1[j] + sbb1[j];
                s_h1[epair + 16][j] = fmaxf(acc[1][jj] + sb1[j], 0.f) * sg1[j] + sbb1[j];
            }
        }
        __syncthreads();

        // layer 2: h2 = relu(h1 @ W2 + b2), each thread: 2 edges x 4 outputs
        {
            float acc[2][4] = {};
            for (int k = 0; k < 128; ++k) {
                float h0 = s_h1[epair][k];
                float h1v = s_h1[epair + 16][k];
                float4 w4 = *(const float4*)&sW2[k][lane16 * 4];
                float w[4] = {w4.x, w4.y, w4.z, w4.w};
#pragma unroll
                for (int q = 0; q < 4; ++q) {
                    acc[0][q] = fmaf(h0, w[q], acc[0][q]);
                    acc[1][q] = fmaf(h1v, w[q], acc[1][q]);
                }
            }
#pragma unroll
            for (int q = 0; q < 4; ++q) {
                int j2 = lane16 * 4 + q;
                s_h2[epair][j2]      = fmaxf(acc[0][q] + sb2[j2], 0.f);
                s_h2[epair + 16][j2] = fmaxf(acc[1][q] + sb2[j2], 0.f);
            }
        }
        __syncthreads();

        // layer 3: dot(h2, W3) + b3 -> sigmoid ; 8 threads per edge
        {
            int e_loc = t >> 3;
            int k8 = (t & 7) * 8;
            float s = 0.f;
#pragma unroll
            for (int q = 0; q < 8; ++q) s = fmaf(s_h2[e_loc][k8 + q], sW3[k8 + q], s);
            s += __shfl_xor(s, 1);
            s += __shfl_xor(s, 2);
            s += __shfl_xor(s, 4);
            int e = tile + e_loc;
            if ((t & 7) == 0 && e < E) out[e] = 1.f / (1.f + expf(-(s + b3)));
        }
        __syncthreads();
    }
}

// =====================================================================================
extern "C" void kernel_launch(void* const* d_in, const int* in_sizes, int n_in,
                              void* d_out, int out_size, void* d_ws, size_t ws_size,
                              hipStream_t stream)
{
    const float* x    = (const float*)d_in[0];
    const float* ea   = (const float*)d_in[1];
    const float* W0   = (const float*)d_in[2];
    const float* We0  = (const float*)d_in[3];
    const float* as0  = (const float*)d_in[4];
    const float* ad0  = (const float*)d_in[5];
    const float* ae0  = (const float*)d_in[6];
    const float* b0   = (const float*)d_in[7];
    const float* bn0g = (const float*)d_in[8];
    const float* bn0b = (const float*)d_in[9];
    const float* W1   = (const float*)d_in[10];
    const float* We1  = (const float*)d_in[11];
    const float* as1  = (const float*)d_in[12];
    const float* ad1  = (const float*)d_in[13];
    const float* ae1  = (const float*)d_in[14];
    const float* b1   = (const float*)d_in[15];
    const float* ndW1 = (const float*)d_in[16];
    const float* ndb1 = (const float*)d_in[17];
    const float* ndg  = (const float*)d_in[18];
    const float* ndbb = (const float*)d_in[19];
    const float* ndW2 = (const float*)d_in[20];
    const float* ndb2 = (const float*)d_in[21];
    const float* ndW3 = (const float*)d_in[22];
    const float* ndb3 = (const float*)d_in[23];
    const float* edW1 = (const float*)d_in[24];
    const float* edb1 = (const float*)d_in[25];
    const float* edg  = (const float*)d_in[26];
    const float* edbb = (const float*)d_in[27];
    const float* edW2 = (const float*)d_in[28];
    const float* edb2 = (const float*)d_in[29];
    const float* edW3 = (const float*)d_in[30];
    const float* edb3 = (const float*)d_in[31];
    const int*   eidx = (const int*)d_in[32];

    const int N = in_sizes[0] / 128;
    const int E = in_sizes[1] / 16;
    const int* srcA = eidx;
    const int* dstA = eidx + E;

    char* ws = (char*)d_ws;
    size_t o = 0;
    auto alloc = [&](size_t bytes) -> void* {
        void* p = ws + o;
        o = (o + bytes + 255) & ~(size_t)255;
        return p;
    };
    float* xw0   = (float*)alloc((size_t)N * 256 * 4);
    float* hbuf  = (float*)alloc((size_t)N * 256 * 4);
    float* a_s0  = (float*)alloc((size_t)N * 4 * 4);
    float* a_d0  = (float*)alloc((size_t)N * 4 * 4);
    float* a_e0a = (float*)alloc((size_t)(E + N) * 4 * 4);
    float* a_e1a = (float*)alloc((size_t)(E + N) * 4);
    float* xw1   = (float*)alloc((size_t)N * 32 * 4);
    float* a_s1  = (float*)alloc((size_t)N * 4);
    float* a_d1  = (float*)alloc((size_t)N * 4);
    float* esum  = (float*)alloc((size_t)N * 16 * 4);  // becomes loop_attr in place
    float* cntf  = (float*)alloc((size_t)N * 4);
    int*   deg   = (int*)alloc((size_t)N * 4);
    int*   rowptr= (int*)alloc((size_t)(N + 1) * 4);
    int*   cur   = (int*)alloc((size_t)N * 4);
    int*   col   = (int*)alloc((size_t)(E + N) * 4);
    float* v0    = (float*)alloc(64 * 4);
    float* v1    = (float*)alloc(16 * 4);
    // node-decoder intermediates alias xw0 (dead after GAT0 aggregation)
    float* n1  = xw0;                      // N*128
    float* h2n = xw0 + (size_t)N * 128;    // N*64

    float* z_out    = (float*)d_out;
    float* node_out = z_out + (size_t)N * 32;
    float* edge_out = node_out + (size_t)N * 128;

    hipMemsetAsync(esum, 0, (size_t)N * 16 * 4, stream);
    hipMemsetAsync(cntf, 0, (size_t)N * 4, stream);

    k_ae_vec<<<1, 128, 0, stream>>>(We0, ae0, We1, ae1, v0, v1);
    k_loop_acc<<<(E * 16 + 255) / 256, 256, 0, stream>>>(ea, dstA, esum, cntf, E);
    k_loop_div<<<(N * 16 + 255) / 256, 256, 0, stream>>>(esum, cntf, N);
    k_deg_init<<<(N + 255) / 256, 256, 0, stream>>>(deg, N);
    k_deg_count<<<(E + 255) / 256, 256, 0, stream>>>(dstA, deg, E);
    k_scan<<<1, 1024, 0, stream>>>(deg, rowptr, cur, N);
    k_fill<<<(E + N + 255) / 256, 256, 0, stream>>>(dstA, cur, col, E, N);

    dim3 g0((N + 63) / 64, 4);
    k_gemm<<<g0, 256, 0, stream>>>(x, W0, xw0, N, 256, 128, nullptr, 0, nullptr, nullptr);
    k_attdots0<<<(N + 3) / 4, 256, 0, stream>>>(xw0, as0, ad0, a_s0, a_d0, N);
    k_edge_ae<<<(E + N + 255) / 256, 256, 0, stream>>>(ea, esum, v0, v1, a_e0a, a_e1a, E, N);
    k_gat0_agg<<<N, 64, 0, stream>>>(rowptr, col, srcA, a_s0, a_d0, a_e0a, xw0, b0, bn0g, bn0b,
                                     hbuf, N, E);

    dim3 g1((N + 63) / 64, 1);
    k_gemm<<<g1, 256, 0, stream>>>(hbuf, W1, xw1, N, 32, 256, nullptr, 0, nullptr, nullptr);
    k_attdots1<<<(N + 255) / 256, 256, 0, stream>>>(xw1, as1, ad1, a_s1, a_d1, N);
    k_gat1_agg<<<N, 64, 0, stream>>>(rowptr, col, srcA, a_s1, a_d1, a_e1a, xw1, b1, z_out, N, E);

    dim3 gn1((N + 63) / 64, 2);
    k_gemm<<<gn1, 256, 0, stream>>>(z_out, ndW1, n1, N, 128, 32, ndb1, 2, ndg, ndbb);
    dim3 gn2((N + 63) / 64, 1);
    k_gemm<<<gn2, 256, 0, stream>>>(n1, ndW2, h2n, N, 64, 128, ndb2, 1, nullptr, nullptr);
    dim3 gn3((N + 63) / 64, 2);
    k_gemm<<<gn3, 256, 0, stream>>>(h2n, ndW3, node_out, N, 128, 64, ndb3, 0, nullptr, nullptr);

    k_edge_dec<<<512, 256, 0, stream>>>(z_out, ea, srcA, dstA, edW1, edb1, edg, edbb,
                                        edW2, edb2, edW3, edb3, edge_out, E);
}

// Round 2
// 882.802 us; speedup vs baseline: 1.6456x; 1.6456x over previous
//
#include <hip/hip_runtime.h>
#include <math.h>

#define BN_K 0.9999950000374997f  // 1/sqrt(1+1e-5)

static __device__ __forceinline__ float lrelu02(float x) { return x > 0.f ? x : 0.2f * x; }

typedef _Float16 half8 __attribute__((ext_vector_type(8)));
typedef float f32x4 __attribute__((ext_vector_type(4)));

static __device__ __forceinline__ unsigned short f2h(float x)
{
    _Float16 h = (_Float16)x;
    union { _Float16 h; unsigned short u; } q;
    q.h = h;
    return q.u;
}

// ---------------- tiny precompute: v0[4][16] = We0[:,h*64:+64] @ ae0[h]; v1[16] = We1 @ ae1 ----
__global__ void k_ae_vec(const float* __restrict__ We0, const float* __restrict__ ae0,
                         const float* __restrict__ We1, const float* __restrict__ ae1,
                         float* __restrict__ v0, float* __restrict__ v1)
{
    int t = threadIdx.x;
    if (t < 64) {
        int h = t >> 4, k = t & 15;
        float s = 0.f;
        for (int c = 0; c < 64; ++c) s += We0[k * 256 + h * 64 + c] * ae0[h * 64 + c];
        v0[h * 16 + k] = s;
    } else if (t < 80) {
        int k = t - 64;
        float s = 0.f;
        for (int c = 0; c < 32; ++c) s += We1[k * 32 + c] * ae1[c];
        v1[k] = s;
    }
}

// ---------------- self-loop edge_attr = scatter-mean over dst ----------------
__global__ void k_loop_acc(const float* __restrict__ ea, const int* __restrict__ dst,
                           float* __restrict__ esum, float* __restrict__ cnt, int E)
{
    int t = blockIdx.x * blockDim.x + threadIdx.x;
    if (t >= E * 16) return;
    int e = t >> 4, k = t & 15;
    int d = dst[e];
    atomicAdd(&esum[(size_t)d * 16 + k], ea[t]);
    if (k == 0) atomicAdd(&cnt[d], 1.f);
}

__global__ void k_loop_div(float* __restrict__ esum, const float* __restrict__ cnt, int N)
{
    int t = blockIdx.x * blockDim.x + threadIdx.x;
    if (t >= N * 16) return;
    int i = t >> 4;
    esum[t] = esum[t] / fmaxf(cnt[i], 1.f);
}

// ---------------- CSR build over dst (self-loops included: deg init = 1) ----------------
__global__ void k_deg_init(int* __restrict__ deg, int N)
{
    int i = blockIdx.x * blockDim.x + threadIdx.x;
    if (i < N) deg[i] = 1;
}

__global__ void k_deg_count(const int* __restrict__ dst, int* __restrict__ deg, int E)
{
    int e = blockIdx.x * blockDim.x + threadIdx.x;
    if (e < E) atomicAdd(&deg[dst[e]], 1);
}

__global__ __launch_bounds__(1024) void k_scan(const int* __restrict__ deg,
                                               int* __restrict__ rowptr,
                                               int* __restrict__ cur, int n)
{
    __shared__ int sbuf[1024];
    int t = threadIdx.x;
    int off = 0;
    for (int base = 0; base < n; base += 1024) {
        int i = base + t;
        int v = (i < n) ? deg[i] : 0;
        sbuf[t] = v;
        __syncthreads();
        for (int d = 1; d < 1024; d <<= 1) {
            int tmp = (t >= d) ? sbuf[t - d] : 0;
            __syncthreads();
            sbuf[t] += tmp;
            __syncthreads();
        }
        int inc = sbuf[t];
        if (i < n) { rowptr[i + 1] = off + inc; cur[i] = off + inc - v; }
        if (base == 0 && t == 0) rowptr[0] = 0;
        int tot = sbuf[1023];
        __syncthreads();
        off += tot;
    }
}

__global__ void k_fill(const int* __restrict__ dst, int* __restrict__ cur,
                       int* __restrict__ col, int E, int N)
{
    int t = blockIdx.x * blockDim.x + threadIdx.x;
    if (t >= E + N) return;
    int d = (t < E) ? dst[t] : (t - E);
    int slot = atomicAdd(&cur[d], 1);
    col[slot] = t;  // eid: t<E original edge; t=E+i self-loop of node i
}

// ---------------- generic fp32 GEMM: C = A[M,K] @ B[K,N] with epilogue ----------------
// mode 0: +bias ; mode 1: relu(+bias) ; mode 2: BN(relu(+bias))
__global__ __launch_bounds__(256) void k_gemm(const float* __restrict__ A,
                                              const float* __restrict__ B,
                                              float* __restrict__ C,
                                              int M, int Nc, int K,
                                              const float* __restrict__ bias, int mode,
                                              const float* __restrict__ g,
                                              const float* __restrict__ bb)
{
    __shared__ float As[16][68];
    __shared__ float Bs[16][68];
    int t = threadIdx.x;
    int tx = t & 15, ty = t >> 4;
    int row0 = blockIdx.x * 64, col0 = blockIdx.y * 64;
    float acc[4][4] = {};
    int r = t >> 2, kk4 = (t & 3) * 4;
    for (int k0 = 0; k0 < K; k0 += 16) {
        {
            int rg = row0 + r;
            float4 av = make_float4(0.f, 0.f, 0.f, 0.f);
            if (rg < M) av = *(const float4*)(A + (size_t)rg * K + k0 + kk4);
            As[kk4 + 0][r] = av.x; As[kk4 + 1][r] = av.y;
            As[kk4 + 2][r] = av.z; As[kk4 + 3][r] = av.w;
        }
        {
            int c = t & 63, kb = t >> 6;
            int cg = col0 + c;
#pragma unroll
            for (int q = 0; q < 4; ++q) {
                int k = kb + q * 4;
                Bs[k][c] = (cg < Nc) ? B[(size_t)(k0 + k) * Nc + cg] : 0.f;
            }
        }
        __syncthreads();
#pragma unroll
        for (int kk = 0; kk < 16; ++kk) {
            float4 a4 = *(const float4*)&As[kk][ty * 4];
            float4 b4 = *(const float4*)&Bs[kk][tx * 4];
            float a[4] = {a4.x, a4.y, a4.z, a4.w};
            float b[4] = {b4.x, b4.y, b4.z, b4.w};
#pragma unroll
            for (int i = 0; i < 4; ++i)
#pragma unroll
                for (int j = 0; j < 4; ++j) acc[i][j] = fmaf(a[i], b[j], acc[i][j]);
        }
        __syncthreads();
    }
#pragma unroll
    for (int i = 0; i < 4; ++i) {
        int row = row0 + ty * 4 + i;
        if (row >= M) continue;
#pragma unroll
        for (int j = 0; j < 4; ++j) {
            int colc = col0 + tx * 4 + j;
            if (colc >= Nc) continue;
            float v = acc[i][j] + (bias ? bias[colc] : 0.f);
            if (mode == 1) v = fmaxf(v, 0.f);
            else if (mode == 2) v = fmaxf(v, 0.f) * (BN_K * g[colc]) + bb[colc];
            C[(size_t)row * Nc + colc] = v;
        }
    }
}

// ---------------- attention source/dest dots, layer 0 (wave per node) ----------------
__global__ void k_attdots0(const float* __restrict__ xw, const float* __restrict__ as0,
                           const float* __restrict__ ad0, float* __restrict__ a_s,
                           float* __restrict__ a_d, int N)
{
    int wid = (blockIdx.x * blockDim.x + threadIdx.x) >> 6;
    int lane = threadIdx.x & 63;
    if (wid >= N) return;
    int h = lane >> 4, c4 = (lane & 15) * 4;
    float4 xv = *(const float4*)(xw + (size_t)wid * 256 + lane * 4);
    float4 sv = *(const float4*)(as0 + h * 64 + c4);
    float4 dv = *(const float4*)(ad0 + h * 64 + c4);
    float ps = xv.x * sv.x + xv.y * sv.y + xv.z * sv.z + xv.w * sv.w;
    float pd = xv.x * dv.x + xv.y * dv.y + xv.z * dv.z + xv.w * dv.w;
#pragma unroll
    for (int m = 1; m < 16; m <<= 1) { ps += __shfl_xor(ps, m); pd += __shfl_xor(pd, m); }
    if ((lane & 15) == 0) { a_s[(size_t)wid * 4 + h] = ps; a_d[(size_t)wid * 4 + h] = pd; }
}

__global__ void k_attdots1(const float* __restrict__ xw, const float* __restrict__ as1,
                           const float* __restrict__ ad1, float* __restrict__ a_s,
                           float* __restrict__ a_d, int N)
{
    int i = blockIdx.x * blockDim.x + threadIdx.x;
    if (i >= N) return;
    float s = 0.f, d = 0.f;
    for (int j = 0; j < 32; ++j) {
        float v = xw[(size_t)i * 32 + j];
        s = fmaf(v, as1[j], s);
        d = fmaf(v, ad1[j], d);
    }
    a_s[i] = s; a_d[i] = d;
}

// ---------------- per-edge attention-edge terms (original edges + self loops) ----------------
__global__ void k_edge_ae(const float* __restrict__ ea, const float* __restrict__ loop_attr,
                          const float* __restrict__ v0, const float* __restrict__ v1,
                          float* __restrict__ a_e0, float* __restrict__ a_e1, int E, int N)
{
    int idx = blockIdx.x * blockDim.x + threadIdx.x;
    if (idx >= E + N) return;
    const float* row = (idx < E) ? (ea + (size_t)idx * 16) : (loop_attr + (size_t)(idx - E) * 16);
    float r[16];
#pragma unroll
    for (int k = 0; k < 16; ++k) r[k] = row[k];
#pragma unroll
    for (int h = 0; h < 4; ++h) {
        float s = 0.f;
#pragma unroll
        for (int k = 0; k < 16; ++k) s = fmaf(r[k], v0[h * 16 + k], s);
        a_e0[(size_t)idx * 4 + h] = s;
    }
    float s1 = 0.f;
#pragma unroll
    for (int k = 0; k < 16; ++k) s1 = fmaf(r[k], v1[k], s1);
    a_e1[idx] = s1;
}

// ---------------- GAT layer 0 aggregation: wave per node, fused +b0 -> BN -> ELU ----------------
__global__ __launch_bounds__(64) void k_gat0_agg(
    const int* __restrict__ rowptr, const int* __restrict__ col, const int* __restrict__ srcA,
    const float* __restrict__ a_s, const float* __restrict__ a_d, const float* __restrict__ a_e,
    const float* __restrict__ xw, const float* __restrict__ b0,
    const float* __restrict__ bng, const float* __restrict__ bnb,
    float* __restrict__ hout, int N, int E)
{
    int i = blockIdx.x;
    int lane = threadIdx.x;
    int beg = rowptr[i], end = rowptr[i + 1];
    float ad[4];
#pragma unroll
    for (int h = 0; h < 4; ++h) ad[h] = a_d[(size_t)i * 4 + h];

    float mx[4] = {-1e30f, -1e30f, -1e30f, -1e30f};
    for (int p = beg + lane; p < end; p += 64) {
        int eid = col[p];
        int s = (eid < E) ? srcA[eid] : i;
        float4 as4 = *(const float4*)(a_s + (size_t)s * 4);
        float4 ae4 = *(const float4*)(a_e + (size_t)eid * 4);
        mx[0] = fmaxf(mx[0], lrelu02(as4.x + ad[0] + ae4.x));
        mx[1] = fmaxf(mx[1], lrelu02(as4.y + ad[1] + ae4.y));
        mx[2] = fmaxf(mx[2], lrelu02(as4.z + ad[2] + ae4.z));
        mx[3] = fmaxf(mx[3], lrelu02(as4.w + ad[3] + ae4.w));
    }
#pragma unroll
    for (int h = 0; h < 4; ++h)
#pragma unroll
        for (int m = 1; m < 64; m <<= 1) mx[h] = fmaxf(mx[h], __shfl_xor(mx[h], m));

    __shared__ float wls[256];
    int hl = lane >> 4;
    float accx = 0.f, accy = 0.f, accz = 0.f, accw = 0.f;
    float s0 = 0.f, s1 = 0.f, s2 = 0.f, s3 = 0.f;
    for (int base = beg; base < end; base += 64) {
        int p = base + lane;
        int cnt = min(64, end - base);
        if (p < end) {
            int eid = col[p];
            int s = (eid < E) ? srcA[eid] : i;
            float4 as4 = *(const float4*)(a_s + (size_t)s * 4);
            float4 ae4 = *(const float4*)(a_e + (size_t)eid * 4);
            float w0 = expf(lrelu02(as4.x + ad[0] + ae4.x) - mx[0]);
            float w1 = expf(lrelu02(as4.y + ad[1] + ae4.y) - mx[1]);
            float w2 = expf(lrelu02(as4.z + ad[2] + ae4.z) - mx[2]);
            float w3 = expf(lrelu02(as4.w + ad[3] + ae4.w) - mx[3]);
            s0 += w0; s1 += w1; s2 += w2; s3 += w3;
            wls[lane * 4 + 0] = w0; wls[lane * 4 + 1] = w1;
            wls[lane * 4 + 2] = w2; wls[lane * 4 + 3] = w3;
        }
        __syncthreads();
        for (int q = 0; q < cnt; ++q) {
            int eid = col[base + q];
            int s = (eid < E) ? srcA[eid] : i;
            float w = wls[q * 4 + hl];
            float4 xv = *(const float4*)(xw + (size_t)s * 256 + lane * 4);
            accx = fmaf(w, xv.x, accx);
            accy = fmaf(w, xv.y, accy);
            accz = fmaf(w, xv.z, accz);
            accw = fmaf(w, xv.w, accw);
        }
        __syncthreads();
    }
#pragma unroll
    for (int m = 1; m < 64; m <<= 1) {
        s0 += __shfl_xor(s0, m); s1 += __shfl_xor(s1, m);
        s2 += __shfl_xor(s2, m); s3 += __shfl_xor(s3, m);
    }
    float sden = ((hl == 0) ? s0 : (hl == 1) ? s1 : (hl == 2) ? s2 : s3) + 1e-16f;

    int ch = lane * 4;
    float out[4] = {accx / sden, accy / sden, accz / sden, accw / sden};
    float4 ov;
    float* po = (float*)&ov;
#pragma unroll
    for (int j = 0; j < 4; ++j) {
        int c = ch + j;
        float v = out[j] + b0[c];
        v = v * (BN_K * bng[c]) + bnb[c];
        po[j] = (v > 0.f) ? v : expm1f(v);
    }
    *(float4*)(hout + (size_t)i * 256 + ch) = ov;
}

// ---------------- GAT layer 1 aggregation: wave per node, fused +b1, writes z ----------------
__global__ __launch_bounds__(64) void k_gat1_agg(
    const int* __restrict__ rowptr, const int* __restrict__ col, const int* __restrict__ srcA,
    const float* __restrict__ a_s, const float* __restrict__ a_d, const float* __restrict__ a_e,
    const float* __restrict__ xw, const float* __restrict__ b1,
    float* __restrict__ zout, int N, int E)
{
    int i = blockIdx.x;
    int lane = threadIdx.x;
    int beg = rowptr[i], end = rowptr[i + 1];
    float ad = a_d[i];
    float mx = -1e30f;
    for (int p = beg + lane; p < end; p += 64) {
        int eid = col[p];
        int s = (eid < E) ? srcA[eid] : i;
        mx = fmaxf(mx, lrelu02(a_s[s] + ad + a_e[eid]));
    }
#pragma unroll
    for (int m = 1; m < 64; m <<= 1) mx = fmaxf(mx, __shfl_xor(mx, m));

    __shared__ float wls[64];
    float acc = 0.f, ssum = 0.f;
    for (int base = beg; base < end; base += 64) {
        int p = base + lane;
        int cnt = min(64, end - base);
        if (p < end) {
            int eid = col[p];
            int s = (eid < E) ? srcA[eid] : i;
            float w = expf(lrelu02(a_s[s] + ad + a_e[eid]) - mx);
            ssum += w;
            wls[lane] = w;
        }
        __syncthreads();
        if (lane < 32) {
            for (int q = 0; q < cnt; ++q) {
                int eid = col[base + q];
                int s = (eid < E) ? srcA[eid] : i;
                acc = fmaf(wls[q], xw[(size_t)s * 32 + lane], acc);
            }
        }
        __syncthreads();
    }
#pragma unroll
    for (int m = 1; m < 64; m <<= 1) ssum += __shfl_xor(ssum, m);
    if (lane < 32) zout[(size_t)i * 32 + lane] = acc / (ssum + 1e-16f) + b1[lane];
}

// ---------------- pack edge-decoder weights into f16 MFMA fragments ----------------
// sigma(g,i) = 8g+i within each 32-wide k-chunk; same mapping used for A and B => layout-proof.
// frag f: 0..23 layer1 (f = c*8 + t, c=kchunk<3, t=ntile<8), 24..39 layer2 (24 + c*4 + t).
// element (f, lane l, i) = W[k = 32c + 8*(l>>4) + i][n = 16t + (l&15)]  (0 if k >= K_real)
__global__ void k_pack_w(const float* __restrict__ W1, const float* __restrict__ W2,
                         unsigned short* __restrict__ pw)
{
    int idx = blockIdx.x * blockDim.x + threadIdx.x;
    if (idx >= 40 * 512) return;
    int f = idx >> 9;
    int l = (idx >> 3) & 63;
    int i = idx & 7;
    int g = l >> 4, m = l & 15;
    float v;
    if (f < 24) {
        int c = f >> 3, t = f & 7;
        int k = 32 * c + 8 * g + i;
        int n = 16 * t + m;
        v = (k < 80) ? W1[k * 128 + n] : 0.f;
    } else {
        int f2 = f - 24;
        int c = f2 >> 2, t = f2 & 3;
        int k = 32 * c + 8 * g + i;
        int n = 16 * t + m;
        v = W2[k * 64 + n];
    }
    pw[idx] = f2h(v);
}

// ---------------- MFMA edge decoder: [zsrc|zdst|ea](80->96) ->128 ->64 ->1 -> sigmoid --------
#define EF_STRIDE 104  // f16 elems per ef row (conflict-breaking pad)
#define H1_STRIDE 136  // f16 elems per h1 row

__global__ __launch_bounds__(256) void k_edge_dec_mfma(
    const float* __restrict__ z, const float* __restrict__ ea,
    const int* __restrict__ srcA, const int* __restrict__ dstA,
    const unsigned short* __restrict__ pw,
    const float* __restrict__ b1, const float* __restrict__ g1, const float* __restrict__ bb1,
    const float* __restrict__ b2, const float* __restrict__ w3, const float* __restrict__ b3v,
    float* __restrict__ out, int E)
{
    __shared__ unsigned short s_pw[40 * 512];
    __shared__ float s_c1[3 * 128];            // b1 | g1*BN_K | bb1
    __shared__ unsigned short s_ef[4][16 * EF_STRIDE];
    __shared__ unsigned short s_h1[4][16 * H1_STRIDE];

    int t = threadIdx.x;
    for (int idx = t; idx < 2560; idx += 256)
        *(half8*)&s_pw[idx * 8] = *(const half8*)&pw[idx * 8];
    if (t < 128) {
        s_c1[t] = b1[t];
        s_c1[128 + t] = g1[t] * BN_K;
        s_c1[256 + t] = bb1[t];
    }
    __syncthreads();

    int wv = t >> 6, lane = t & 63;
    int g = lane >> 4, m = lane & 15;
    unsigned short* ef = s_ef[wv];
    unsigned short* h1 = s_h1[wv];

    float w3t[4], b2t[4];
#pragma unroll
    for (int q = 0; q < 4; ++q) { w3t[q] = w3[16 * q + m]; b2t[q] = b2[16 * q + m]; }
    float b3 = b3v[0];

    {   // zero-pad ef k=80..95 once (never overwritten)
        int r = lane >> 2, c0 = (lane & 3) * 4;
#pragma unroll
        for (int q = 0; q < 4; ++q) ef[r * EF_STRIDE + 80 + c0 + q] = 0;
    }

    int ntiles = (E + 15) >> 4;
    int gw = blockIdx.x * 4 + wv;
    int nw = gridDim.x * 4;

    for (int tile = gw; tile < ntiles; tile += nw) {
        int e0 = tile << 4;
        // ---- stage: lane covers row m (edge e0+m), k-part g (floats [20g, 20g+20))
        int e = e0 + m;
        bool ok = (e < E);
        int si = ok ? srcA[e] : 0;
        int di = ok ? dstA[e] : 0;
#pragma unroll
        for (int q = 0; q < 5; ++q) {
            int f = 20 * g + 4 * q;
            float4 v = make_float4(0.f, 0.f, 0.f, 0.f);
            if (ok) {
                if (f < 32)       v = *(const float4*)(z + (size_t)si * 32 + f);
                else if (f < 64)  v = *(const float4*)(z + (size_t)di * 32 + (f - 32));
                else              v = *(const float4*)(ea + (size_t)e * 16 + (f - 64));
            }
            ushort4 bv;
            bv.x = f2h(v.x); bv.y = f2h(v.y); bv.z = f2h(v.z); bv.w = f2h(v.w);
            *(ushort4*)&ef[m * EF_STRIDE + f] = bv;
        }
        asm volatile("s_waitcnt lgkmcnt(0)" ::: "memory");
        __builtin_amdgcn_sched_barrier(0);

        // ---- layer 1: [16,96] x [96,128] via 3 kchunks x 8 ntiles
        f32x4 acc1[8] = {};
#pragma unroll
        for (int c = 0; c < 3; ++c) {
            half8 a = *(half8*)&ef[m * EF_STRIDE + 32 * c + 8 * g];
#pragma unroll
            for (int tt = 0; tt < 8; ++tt) {
                half8 w = *(const half8*)&s_pw[(c * 8 + tt) * 512 + lane * 8];
                acc1[tt] = __builtin_amdgcn_mfma_f32_16x16x32_f16(a, w, acc1[tt], 0, 0, 0);
            }
        }
        // epilogue: BN(relu(+b1)) -> f16 into h1_lds. D: row(edge)=4g+r, col=16tt+m
#pragma unroll
        for (int tt = 0; tt < 8; ++tt) {
            int col = 16 * tt + m;
            float cb = s_c1[col], cg = s_c1[128 + col], cb2 = s_c1[256 + col];
#pragma unroll
            for (int r = 0; r < 4; ++r) {
                float v = fmaxf(acc1[tt][r] + cb, 0.f) * cg + cb2;
                h1[(4 * g + r) * H1_STRIDE + col] = f2h(v);
            }
        }
        asm volatile("s_waitcnt lgkmcnt(0)" ::: "memory");
        __builtin_amdgcn_sched_barrier(0);

        // ---- layer 2: [16,128] x [128,64] via 4 kchunks x 4 ntiles
        f32x4 acc2[4] = {};
#pragma unroll
        for (int c = 0; c < 4; ++c) {
            half8 a = *(half8*)&h1[m * H1_STRIDE + 32 * c + 8 * g];
#pragma unroll
            for (int tt = 0; tt < 4; ++tt) {
                half8 w = *(const half8*)&s_pw[(24 + c * 4 + tt) * 512 + lane * 8];
                acc2[tt] = __builtin_amdgcn_mfma_f32_16x16x32_f16(a, w, acc2[tt], 0, 0, 0);
            }
        }
        // ---- layer 3: relu(+b2) dot w3, reduce over 16 lanes, sigmoid, store
        float s[4];
#pragma unroll
        for (int r = 0; r < 4; ++r) {
            float acc = 0.f;
#pragma unroll
            for (int tt = 0; tt < 4; ++tt) {
                float v = fmaxf(acc2[tt][r] + b2t[tt], 0.f);
                acc = fmaf(v, w3t[tt], acc);
            }
            acc += __shfl_xor(acc, 1);
            acc += __shfl_xor(acc, 2);
            acc += __shfl_xor(acc, 4);
            acc += __shfl_xor(acc, 8);
            s[r] = acc;
        }
        if (m == 0) {
            int eb = e0 + 4 * g;
            if (eb + 3 < E) {
                float4 o;
                o.x = 1.f / (1.f + expf(-(s[0] + b3)));
                o.y = 1.f / (1.f + expf(-(s[1] + b3)));
                o.z = 1.f / (1.f + expf(-(s[2] + b3)));
                o.w = 1.f / (1.f + expf(-(s[3] + b3)));
                *(float4*)(out + eb) = o;
            } else {
#pragma unroll
                for (int r = 0; r < 4; ++r)
                    if (eb + r < E) out[eb + r] = 1.f / (1.f + expf(-(s[r] + b3)));
            }
        }
    }
}

// =====================================================================================
extern "C" void kernel_launch(void* const* d_in, const int* in_sizes, int n_in,
                              void* d_out, int out_size, void* d_ws, size_t ws_size,
                              hipStream_t stream)
{
    const float* x    = (const float*)d_in[0];
    const float* ea   = (const float*)d_in[1];
    const float* W0   = (const float*)d_in[2];
    const float* We0  = (const float*)d_in[3];
    const float* as0  = (const float*)d_in[4];
    const float* ad0  = (const float*)d_in[5];
    const float* ae0  = (const float*)d_in[6];
    const float* b0   = (const float*)d_in[7];
    const float* bn0g = (const float*)d_in[8];
    const float* bn0b = (const float*)d_in[9];
    const float* W1   = (const float*)d_in[10];
    const float* We1  = (const float*)d_in[11];
    const float* as1  = (const float*)d_in[12];
    const float* ad1  = (const float*)d_in[13];
    const float* ae1  = (const float*)d_in[14];
    const float* b1   = (const float*)d_in[15];
    const float* ndW1 = (const float*)d_in[16];
    const float* ndb1 = (const float*)d_in[17];
    const float* ndg  = (const float*)d_in[18];
    const float* ndbb = (const float*)d_in[19];
    const float* ndW2 = (const float*)d_in[20];
    const float* ndb2 = (const float*)d_in[21];
    const float* ndW3 = (const float*)d_in[22];
    const float* ndb3 = (const float*)d_in[23];
    const float* edW1 = (const float*)d_in[24];
    const float* edb1 = (const float*)d_in[25];
    const float* edg  = (const float*)d_in[26];
    const float* edbb = (const float*)d_in[27];
    const float* edW2 = (const float*)d_in[28];
    const float* edb2 = (const float*)d_in[29];
    const float* edW3 = (const float*)d_in[30];
    const float* edb3 = (const float*)d_in[31];
    const int*   eidx = (const int*)d_in[32];

    const int N = in_sizes[0] / 128;
    const int E = in_sizes[1] / 16;
    const int* srcA = eidx;
    const int* dstA = eidx + E;

    char* ws = (char*)d_ws;
    size_t o = 0;
    auto alloc = [&](size_t bytes) -> void* {
        void* p = ws + o;
        o = (o + bytes + 255) & ~(size_t)255;
        return p;
    };
    float* xw0   = (float*)alloc((size_t)N * 256 * 4);
    float* hbuf  = (float*)alloc((size_t)N * 256 * 4);
    float* a_s0  = (float*)alloc((size_t)N * 4 * 4);
    float* a_d0  = (float*)alloc((size_t)N * 4 * 4);
    float* a_e0a = (float*)alloc((size_t)(E + N) * 4 * 4);
    float* a_e1a = (float*)alloc((size_t)(E + N) * 4);
    float* xw1   = (float*)alloc((size_t)N * 32 * 4);
    float* a_s1  = (float*)alloc((size_t)N * 4);
    float* a_d1  = (float*)alloc((size_t)N * 4);
    float* esum  = (float*)alloc((size_t)N * 16 * 4);  // becomes loop_attr in place
    float* cntf  = (float*)alloc((size_t)N * 4);
    int*   deg   = (int*)alloc((size_t)N * 4);
    int*   rowptr= (int*)alloc((size_t)(N + 1) * 4);
    int*   cur   = (int*)alloc((size_t)N * 4);
    int*   col   = (int*)alloc((size_t)(E + N) * 4);
    float* v0    = (float*)alloc(64 * 4);
    float* v1    = (float*)alloc(16 * 4);
    unsigned short* pw = (unsigned short*)alloc(40 * 512 * 2);
    // node-decoder intermediates alias xw0 (dead after GAT0 aggregation)
    float* n1  = xw0;                      // N*128
    float* h2n = xw0 + (size_t)N * 128;    // N*64

    float* z_out    = (float*)d_out;
    float* node_out = z_out + (size_t)N * 32;
    float* edge_out = node_out + (size_t)N * 128;

    hipMemsetAsync(esum, 0, (size_t)N * 16 * 4, stream);
    hipMemsetAsync(cntf, 0, (size_t)N * 4, stream);

    k_ae_vec<<<1, 128, 0, stream>>>(We0, ae0, We1, ae1, v0, v1);
    k_pack_w<<<80, 256, 0, stream>>>(edW1, edW2, pw);
    k_loop_acc<<<(E * 16 + 255) / 256, 256, 0, stream>>>(ea, dstA, esum, cntf, E);
    k_loop_div<<<(N * 16 + 255) / 256, 256, 0, stream>>>(esum, cntf, N);
    k_deg_init<<<(N + 255) / 256, 256, 0, stream>>>(deg, N);
    k_deg_count<<<(E + 255) / 256, 256, 0, stream>>>(dstA, deg, E);
    k_scan<<<1, 1024, 0, stream>>>(deg, rowptr, cur, N);
    k_fill<<<(E + N + 255) / 256, 256, 0, stream>>>(dstA, cur, col, E, N);

    dim3 g0((N + 63) / 64, 4);
    k_gemm<<<g0, 256, 0, stream>>>(x, W0, xw0, N, 256, 128, nullptr, 0, nullptr, nullptr);
    k_attdots0<<<(N + 3) / 4, 256, 0, stream>>>(xw0, as0, ad0, a_s0, a_d0, N);
    k_edge_ae<<<(E + N + 255) / 256, 256, 0, stream>>>(ea, esum, v0, v1, a_e0a, a_e1a, E, N);
    k_gat0_agg<<<N, 64, 0, stream>>>(rowptr, col, srcA, a_s0, a_d0, a_e0a, xw0, b0, bn0g, bn0b,
                                     hbuf, N, E);

    dim3 g1((N + 63) / 64, 1);
    k_gemm<<<g1, 256, 0, stream>>>(hbuf, W1, xw1, N, 32, 256, nullptr, 0, nullptr, nullptr);
    k_attdots1<<<(N + 255) / 256, 256, 0, stream>>>(xw1, as1, ad1, a_s1, a_d1, N);
    k_gat1_agg<<<N, 64, 0, stream>>>(rowptr, col, srcA, a_s1, a_d1, a_e1a, xw1, b1, z_out, N, E);

    dim3 gn1((N + 63) / 64, 2);
    k_gemm<<<gn1, 256, 0, stream>>>(z_out, ndW1, n1, N, 128, 32, ndb1, 2, ndg, ndbb);
    dim3 gn2((N + 63) / 64, 1);
    k_gemm<<<gn2, 256, 0, stream>>>(n1, ndW2, h2n, N, 64, 128, ndb2, 1, nullptr, nullptr);
    dim3 gn3((N + 63) / 64, 2);
    k_gemm<<<gn3, 256, 0, stream>>>(h2n, ndW3, node_out, N, 128, 64, ndb3, 0, nullptr, nullptr);

    k_edge_dec_mfma<<<1024, 256, 0, stream>>>(z_out, ea, srcA, dstA, pw,
                                              edb1, edg, edbb, edb2, edW3, edb3, edge_out, E);
}

// Round 3
// 643.426 us; speedup vs baseline: 2.2578x; 1.3720x over previous
//
#include <hip/hip_runtime.h>
#include <math.h>

#define BN_K 0.9999950000374997f  // 1/sqrt(1+1e-5)

static __device__ __forceinline__ float lrelu02(float x) { return x > 0.f ? x : 0.2f * x; }

typedef _Float16 half8 __attribute__((ext_vector_type(8)));
typedef float f32x4 __attribute__((ext_vector_type(4)));

static __device__ __forceinline__ unsigned short f2h(float x)
{
    union { _Float16 h; unsigned short u; } q;
    q.h = (_Float16)x;
    return q.u;
}
static __device__ __forceinline__ float h2f(unsigned short u)
{
    union { unsigned short u; _Float16 h; } q;
    q.u = u;
    return (float)q.h;
}

// ---------------- tiny precompute: v0[4][16] = We0[:,h*64:+64] @ ae0[h]; v1[16] = We1 @ ae1 ----
__global__ void k_ae_vec(const float* __restrict__ We0, const float* __restrict__ ae0,
                         const float* __restrict__ We1, const float* __restrict__ ae1,
                         float* __restrict__ v0, float* __restrict__ v1)
{
    int t = threadIdx.x;
    if (t < 64) {
        int h = t >> 4, k = t & 15;
        float s = 0.f;
        for (int c = 0; c < 64; ++c) s += We0[k * 256 + h * 64 + c] * ae0[h * 64 + c];
        v0[h * 16 + k] = s;
    } else if (t < 80) {
        int k = t - 64;
        float s = 0.f;
        for (int c = 0; c < 32; ++c) s += We1[k * 32 + c] * ae1[c];
        v1[k] = s;
    }
}

// ---------------- fp32 -> f16 convert ----------------
__global__ void k_cvt(const float* __restrict__ in, unsigned short* __restrict__ out, long n)
{
    long i = ((long)blockIdx.x * blockDim.x + threadIdx.x) * 4;
    if (i + 3 < n) {
        float4 v = *(const float4*)(in + i);
        ushort4 o;
        o.x = f2h(v.x); o.y = f2h(v.y); o.z = f2h(v.z); o.w = f2h(v.w);
        *(ushort4*)(out + i) = o;
    } else {
        for (; i < n; ++i) out[i] = f2h(in[i]);
    }
}

// ---------------- CSR build over dst (self-loops included: deg init = 1) ----------------
__global__ void k_deg_init(int* __restrict__ deg, int N)
{
    int i = blockIdx.x * blockDim.x + threadIdx.x;
    if (i < N) deg[i] = 1;
}

__global__ void k_deg_count(const int* __restrict__ dst, int* __restrict__ deg, int E)
{
    int e = blockIdx.x * blockDim.x + threadIdx.x;
    if (e < E) atomicAdd(&deg[dst[e]], 1);
}

__global__ __launch_bounds__(1024) void k_scan(const int* __restrict__ deg,
                                               int* __restrict__ rowptr,
                                               int* __restrict__ cur, int n)
{
    __shared__ int sbuf[1024];
    int t = threadIdx.x;
    int off = 0;
    for (int base = 0; base < n; base += 1024) {
        int i = base + t;
        int v = (i < n) ? deg[i] : 0;
        sbuf[t] = v;
        __syncthreads();
        for (int d = 1; d < 1024; d <<= 1) {
            int tmp = (t >= d) ? sbuf[t - d] : 0;
            __syncthreads();
            sbuf[t] += tmp;
            __syncthreads();
        }
        int inc = sbuf[t];
        if (i < n) { rowptr[i + 1] = off + inc; cur[i] = off + inc - v; }
        if (base == 0 && t == 0) rowptr[0] = 0;
        int tot = sbuf[1023];
        __syncthreads();
        off += tot;
    }
}

__global__ void k_fill(const int* __restrict__ dst, int* __restrict__ cur,
                       int* __restrict__ col, int E, int N)
{
    int t = blockIdx.x * blockDim.x + threadIdx.x;
    if (t >= E + N) return;
    int d = (t < E) ? dst[t] : (t - E);
    int slot = atomicAdd(&cur[d], 1);
    col[slot] = t;  // eid: t<E original edge; t=E+i self-loop of node i
}

// ---------------- self-loop edge_attr = scatter-mean via CSR (replaces atomics) ----------------
__global__ __launch_bounds__(256) void k_loop_mean(
    const int* __restrict__ rowptr, const int* __restrict__ col,
    const float* __restrict__ ea, float* __restrict__ loop_attr, int N, int E)
{
    int wv = threadIdx.x >> 6, lane = threadIdx.x & 63;
    int i = blockIdx.x * 4 + wv;
    if (i >= N) return;
    int beg = rowptr[i], end = rowptr[i + 1];
    int q = lane >> 4, k = lane & 15;
    float sum = 0.f;
    for (int p = beg + q; p < end; p += 4) {
        int eid = col[p];
        if (eid < E) sum += ea[(size_t)eid * 16 + k];
    }
    sum += __shfl_xor(sum, 16);
    sum += __shfl_xor(sum, 32);
    if (lane < 16) {
        int cnt = end - beg - 1;  // exactly one self-loop per node
        loop_attr[(size_t)i * 16 + k] = sum / (float)max(cnt, 1);
    }
}

// ---------------- per-edge attention-edge terms + ea16 emit ----------------
__global__ void k_edge_ae(const float* __restrict__ ea, const float* __restrict__ loop_attr,
                          const float* __restrict__ v0, const float* __restrict__ v1,
                          float* __restrict__ a_e0, float* __restrict__ a_e1,
                          unsigned short* __restrict__ ea16, int E, int N)
{
    int idx = blockIdx.x * blockDim.x + threadIdx.x;
    if (idx >= E + N) return;
    const float* row = (idx < E) ? (ea + (size_t)idx * 16) : (loop_attr + (size_t)(idx - E) * 16);
    float r[16];
#pragma unroll
    for (int k = 0; k < 16; ++k) r[k] = row[k];
#pragma unroll
    for (int h = 0; h < 4; ++h) {
        float s = 0.f;
#pragma unroll
        for (int k = 0; k < 16; ++k) s = fmaf(r[k], v0[h * 16 + k], s);
        a_e0[(size_t)idx * 4 + h] = s;
    }
    float s1 = 0.f;
#pragma unroll
    for (int k = 0; k < 16; ++k) s1 = fmaf(r[k], v1[k], s1);
    a_e1[idx] = s1;
    if (idx < E) {
#pragma unroll
        for (int k = 0; k < 16; k += 4) {
            ushort4 o;
            o.x = f2h(r[k]); o.y = f2h(r[k + 1]); o.z = f2h(r[k + 2]); o.w = f2h(r[k + 3]);
            *(ushort4*)(ea16 + (size_t)idx * 16 + k) = o;
        }
    }
}

// ---------------- pack ALL weights into f16 MFMA fragments ----------------
// sigma(g,i)=8g+i; element (frag f, lane l, i) = W[k=32c+8g+i][n=16t+m], 0 if k>=K.
// frag ranges: [0,64) W0(128,256) c*16+t | [64,80) W1(256,32) c*2+t | [80,88) ndW1(32,128) t
// [88,104) ndW2(128,64) c*4+t | [104,120) ndW3(64,128) c*8+t | [120,144) edW1(80->96,128) c*8+t
// [144,160) edW2(128,64) c*4+t
__global__ __launch_bounds__(512) void k_pack_all(
    const float* __restrict__ W0, const float* __restrict__ W1,
    const float* __restrict__ nd1, const float* __restrict__ nd2, const float* __restrict__ nd3,
    const float* __restrict__ ed1, const float* __restrict__ ed2,
    unsigned short* __restrict__ pw)
{
    int f = blockIdx.x, t = threadIdx.x;
    int l = t >> 3, i = t & 7, g = l >> 4, m = l & 15;
    const float* W; int K, Nn, c, tt;
    if (f < 64)       { W = W0;  K = 128; Nn = 256; int q = f;       c = q >> 4; tt = q & 15; }
    else if (f < 80)  { W = W1;  K = 256; Nn = 32;  int q = f - 64;  c = q >> 1; tt = q & 1;  }
    else if (f < 88)  { W = nd1; K = 32;  Nn = 128; int q = f - 80;  c = 0;      tt = q;      }
    else if (f < 104) { W = nd2; K = 128; Nn = 64;  int q = f - 88;  c = q >> 2; tt = q & 3;  }
    else if (f < 120) { W = nd3; K = 64;  Nn = 128; int q = f - 104; c = q >> 3; tt = q & 7;  }
    else if (f < 144) { W = ed1; K = 80;  Nn = 128; int q = f - 120; c = q >> 3; tt = q & 7;  }
    else              { W = ed2; K = 128; Nn = 64;  int q = f - 144; c = q >> 2; tt = q & 3;  }
    int k = 32 * c + 8 * g + i, n = 16 * tt + m;
    float v = (k < K) ? W[(size_t)k * Nn + n] : 0.f;
    pw[(size_t)f * 512 + t] = f2h(v);
}

// ---------------- generic f16 MFMA GEMM: out = A16[M,K] @ B(frags) with epilogue ----------------
// MODE 0: raw -> f16 ; 1: relu(+bias) -> f16 ; 2: BN(relu(+bias)) -> f16 ; 3: +bias -> fp32
template <int KC, int NT, int MODE>
__global__ __launch_bounds__(256) void k_gemm16(
    const unsigned short* __restrict__ A16, const unsigned short* __restrict__ pwB,
    void* __restrict__ outp, int M,
    const float* __restrict__ bias, const float* __restrict__ g_,
    const float* __restrict__ bb_)
{
    constexpr int K = KC * 32;
    constexpr int LDA = K + 8;
    __shared__ unsigned short s_pw[KC * NT * 512];
    __shared__ unsigned short s_a[64 * LDA];
    __shared__ float s_c[3 * NT * 16];

    int t = threadIdx.x;
    for (int idx = t; idx < KC * NT * 64; idx += 256)
        *(half8*)&s_pw[idx * 8] = *(const half8*)&pwB[idx * 8];
    if (MODE) {
        for (int c = t; c < NT * 16; c += 256) {
            s_c[c] = bias[c];
            if (MODE == 2) { s_c[NT * 16 + c] = g_[c] * BN_K; s_c[2 * NT * 16 + c] = bb_[c]; }
        }
    }
    int wv = t >> 6, lane = t & 63, gq = lane >> 4, m = lane & 15;
    int nrt = (M + 63) >> 6;
    for (int rt = blockIdx.x; rt < nrt; rt += gridDim.x) {
        int r0 = rt << 6;
        __syncthreads();
        for (int idx = t; idx < 64 * (K / 8); idx += 256) {
            int row = idx / (K / 8), cb = idx % (K / 8);
            half8 v = {};
            if (r0 + row < M) v = *(const half8*)&A16[(size_t)(r0 + row) * K + cb * 8];
            *(half8*)&s_a[row * LDA + cb * 8] = v;
        }
        __syncthreads();
        f32x4 acc[NT] = {};
#pragma unroll
        for (int c = 0; c < KC; ++c) {
            half8 a = *(half8*)&s_a[(wv * 16 + m) * LDA + 32 * c + 8 * gq];
#pragma unroll
            for (int tt = 0; tt < NT; ++tt) {
                half8 b = *(const half8*)&s_pw[(c * NT + tt) * 512 + lane * 8];
                acc[tt] = __builtin_amdgcn_mfma_f32_16x16x32_f16(a, b, acc[tt], 0, 0, 0);
            }
        }
#pragma unroll
        for (int tt = 0; tt < NT; ++tt) {
            int col = 16 * tt + m;
            float cb = MODE ? s_c[col] : 0.f;
#pragma unroll
            for (int r = 0; r < 4; ++r) {
                int row = r0 + wv * 16 + 4 * gq + r;
                float v = acc[tt][r] + cb;
                if (MODE == 1) v = fmaxf(v, 0.f);
                if (MODE == 2) v = fmaxf(v, 0.f) * s_c[NT * 16 + col] + s_c[2 * NT * 16 + col];
                if (MODE == 3) {
                    if (row < M) ((float*)outp)[(size_t)row * (NT * 16) + col] = v;
                } else {
                    float o = __shfl_xor(v, 1);
                    if (!(m & 1) && row < M) {
                        unsigned int u = (unsigned)f2h(v) | ((unsigned)f2h(o) << 16);
                        *(unsigned int*)&((unsigned short*)outp)[(size_t)row * (NT * 16) + col] = u;
                    }
                }
            }
        }
    }
}

// ---------------- attention source/dest dots, layer 0 (wave per node, f16 xw) ----------------
__global__ void k_attdots0(const unsigned short* __restrict__ xw16, const float* __restrict__ as0,
                           const float* __restrict__ ad0, float* __restrict__ a_s,
                           float* __restrict__ a_d, int N)
{
    int wid = (blockIdx.x * blockDim.x + threadIdx.x) >> 6;
    int lane = threadIdx.x & 63;
    if (wid >= N) return;
    int h = lane >> 4, c4 = (lane & 15) * 4;
    ushort4 xv4 = *(const ushort4*)(xw16 + (size_t)wid * 256 + lane * 4);
    float4 sv = *(const float4*)(as0 + h * 64 + c4);
    float4 dv = *(const float4*)(ad0 + h * 64 + c4);
    float x0 = h2f(xv4.x), x1 = h2f(xv4.y), x2 = h2f(xv4.z), x3 = h2f(xv4.w);
    float ps = x0 * sv.x + x1 * sv.y + x2 * sv.z + x3 * sv.w;
    float pd = x0 * dv.x + x1 * dv.y + x2 * dv.z + x3 * dv.w;
#pragma unroll
    for (int mm = 1; mm < 16; mm <<= 1) { ps += __shfl_xor(ps, mm); pd += __shfl_xor(pd, mm); }
    if ((lane & 15) == 0) { a_s[(size_t)wid * 4 + h] = ps; a_d[(size_t)wid * 4 + h] = pd; }
}

__global__ void k_attdots1(const unsigned short* __restrict__ xw16, const float* __restrict__ as1,
                           const float* __restrict__ ad1, float* __restrict__ a_s,
                           float* __restrict__ a_d, int N)
{
    int i = blockIdx.x * blockDim.x + threadIdx.x;
    if (i >= N) return;
    float s = 0.f, d = 0.f;
    for (int j0 = 0; j0 < 32; j0 += 4) {
        ushort4 v4 = *(const ushort4*)(xw16 + (size_t)i * 32 + j0);
        float v[4] = {h2f(v4.x), h2f(v4.y), h2f(v4.z), h2f(v4.w)};
#pragma unroll
        for (int j = 0; j < 4; ++j) {
            s = fmaf(v[j], as1[j0 + j], s);
            d = fmaf(v[j], ad1[j0 + j], d);
        }
    }
    a_s[i] = s; a_d[i] = d;
}

// ---------------- GAT layer 0 aggregation: wave per node, f16 gather, fused BN/ELU ------------
__global__ __launch_bounds__(64) void k_gat0_agg(
    const int* __restrict__ rowptr, const int* __restrict__ col, const int* __restrict__ srcA,
    const float* __restrict__ a_s, const float* __restrict__ a_d, const float* __restrict__ a_e,
    const unsigned short* __restrict__ xw16, const float* __restrict__ b0,
    const float* __restrict__ bng, const float* __restrict__ bnb,
    unsigned short* __restrict__ hout16, int N, int E)
{
    int i = blockIdx.x;
    int lane = threadIdx.x;
    int beg = rowptr[i], end = rowptr[i + 1];
    float ad[4];
#pragma unroll
    for (int h = 0; h < 4; ++h) ad[h] = a_d[(size_t)i * 4 + h];

    float mx[4] = {-1e30f, -1e30f, -1e30f, -1e30f};
    for (int p = beg + lane; p < end; p += 64) {
        int eid = col[p];
        int s = (eid < E) ? srcA[eid] : i;
        float4 as4 = *(const float4*)(a_s + (size_t)s * 4);
        float4 ae4 = *(const float4*)(a_e + (size_t)eid * 4);
        mx[0] = fmaxf(mx[0], lrelu02(as4.x + ad[0] + ae4.x));
        mx[1] = fmaxf(mx[1], lrelu02(as4.y + ad[1] + ae4.y));
        mx[2] = fmaxf(mx[2], lrelu02(as4.z + ad[2] + ae4.z));
        mx[3] = fmaxf(mx[3], lrelu02(as4.w + ad[3] + ae4.w));
    }
#pragma unroll
    for (int h = 0; h < 4; ++h)
#pragma unroll
        for (int m = 1; m < 64; m <<= 1) mx[h] = fmaxf(mx[h], __shfl_xor(mx[h], m));

    __shared__ float wls[256];
    int hl = lane >> 4;
    float accx = 0.f, accy = 0.f, accz = 0.f, accw = 0.f;
    float s0 = 0.f, s1 = 0.f, s2 = 0.f, s3 = 0.f;
    for (int base = beg; base < end; base += 64) {
        int p = base + lane;
        int cnt = min(64, end - base);
        if (p < end) {
            int eid = col[p];
            int s = (eid < E) ? srcA[eid] : i;
            float4 as4 = *(const float4*)(a_s + (size_t)s * 4);
            float4 ae4 = *(const float4*)(a_e + (size_t)eid * 4);
            float w0 = expf(lrelu02(as4.x + ad[0] + ae4.x) - mx[0]);
            float w1 = expf(lrelu02(as4.y + ad[1] + ae4.y) - mx[1]);
            float w2 = expf(lrelu02(as4.z + ad[2] + ae4.z) - mx[2]);
            float w3 = expf(lrelu02(as4.w + ad[3] + ae4.w) - mx[3]);
            s0 += w0; s1 += w1; s2 += w2; s3 += w3;
            wls[lane * 4 + 0] = w0; wls[lane * 4 + 1] = w1;
            wls[lane * 4 + 2] = w2; wls[lane * 4 + 3] = w3;
        }
        __syncthreads();
        for (int q = 0; q < cnt; ++q) {
            int eid = col[base + q];
            int s = (eid < E) ? srcA[eid] : i;
            float w = wls[q * 4 + hl];
            ushort4 xv = *(const ushort4*)(xw16 + (size_t)s * 256 + lane * 4);
            accx = fmaf(w, h2f(xv.x), accx);
            accy = fmaf(w, h2f(xv.y), accy);
            accz = fmaf(w, h2f(xv.z), accz);
            accw = fmaf(w, h2f(xv.w), accw);
        }
        __syncthreads();
    }
#pragma unroll
    for (int m = 1; m < 64; m <<= 1) {
        s0 += __shfl_xor(s0, m); s1 += __shfl_xor(s1, m);
        s2 += __shfl_xor(s2, m); s3 += __shfl_xor(s3, m);
    }
    float sden = ((hl == 0) ? s0 : (hl == 1) ? s1 : (hl == 2) ? s2 : s3) + 1e-16f;

    int ch = lane * 4;
    float out[4] = {accx / sden, accy / sden, accz / sden, accw / sden};
    ushort4 ov;
    unsigned short* po = (unsigned short*)&ov;
#pragma unroll
    for (int j = 0; j < 4; ++j) {
        int c = ch + j;
        float v = out[j] + b0[c];
        v = v * (BN_K * bng[c]) + bnb[c];
        po[j] = f2h((v > 0.f) ? v : expm1f(v));
    }
    *(ushort4*)(hout16 + (size_t)i * 256 + ch) = ov;
}

// ---------------- GAT layer 1 aggregation: f16 gather, writes z (fp32) + z16 ----------------
__global__ __launch_bounds__(64) void k_gat1_agg(
    const int* __restrict__ rowptr, const int* __restrict__ col, const int* __restrict__ srcA,
    const float* __restrict__ a_s, const float* __restrict__ a_d, const float* __restrict__ a_e,
    const unsigned short* __restrict__ xw16, const float* __restrict__ b1,
    float* __restrict__ zout, unsigned short* __restrict__ z16, int N, int E)
{
    int i = blockIdx.x;
    int lane = threadIdx.x;
    int beg = rowptr[i], end = rowptr[i + 1];
    float ad = a_d[i];
    float mx = -1e30f;
    for (int p = beg + lane; p < end; p += 64) {
        int eid = col[p];
        int s = (eid < E) ? srcA[eid] : i;
        mx = fmaxf(mx, lrelu02(a_s[s] + ad + a_e[eid]));
    }
#pragma unroll
    for (int m = 1; m < 64; m <<= 1) mx = fmaxf(mx, __shfl_xor(mx, m));

    __shared__ float wls[64];
    float acc = 0.f, ssum = 0.f;
    for (int base = beg; base < end; base += 64) {
        int p = base + lane;
        int cnt = min(64, end - base);
        if (p < end) {
            int eid = col[p];
            int s = (eid < E) ? srcA[eid] : i;
            float w = expf(lrelu02(a_s[s] + ad + a_e[eid]) - mx);
            ssum += w;
            wls[lane] = w;
        }
        __syncthreads();
        if (lane < 32) {
            for (int q = 0; q < cnt; ++q) {
                int eid = col[base + q];
                int s = (eid < E) ? srcA[eid] : i;
                acc = fmaf(wls[q], h2f(xw16[(size_t)s * 32 + lane]), acc);
            }
        }
        __syncthreads();
    }
#pragma unroll
    for (int m = 1; m < 64; m <<= 1) ssum += __shfl_xor(ssum, m);
    if (lane < 32) {
        float v = acc / (ssum + 1e-16f) + b1[lane];
        zout[(size_t)i * 32 + lane] = v;
        z16[(size_t)i * 32 + lane] = f2h(v);
    }
}

// ---------------- MFMA edge decoder (stages from z16/ea16) ----------------
#define EF_STRIDE 104
#define H1_STRIDE 136

__global__ __launch_bounds__(256) void k_edge_dec_mfma(
    const unsigned short* __restrict__ z16, const unsigned short* __restrict__ ea16,
    const int* __restrict__ srcA, const int* __restrict__ dstA,
    const unsigned short* __restrict__ pw,  // pre-offset to edW1 frags
    const float* __restrict__ b1, const float* __restrict__ b2,
    const float* __restrict__ w3, const float* __restrict__ b3v,
    const float* __restrict__ g1, const float* __restrict__ bb1,
    float* __restrict__ out, int E)
{
    __shared__ unsigned short s_pw[40 * 512];
    __shared__ float s_c1[3 * 128];
    __shared__ unsigned short s_ef[4][16 * EF_STRIDE];
    __shared__ unsigned short s_h1[4][16 * H1_STRIDE];

    int t = threadIdx.x;
    for (int idx = t; idx < 2560; idx += 256)
        *(half8*)&s_pw[idx * 8] = *(const half8*)&pw[idx * 8];
    if (t < 128) {
        s_c1[t] = b1[t];
        s_c1[128 + t] = g1[t] * BN_K;
        s_c1[256 + t] = bb1[t];
    }
    __syncthreads();

    int wv = t >> 6, lane = t & 63;
    int g = lane >> 4, m = lane & 15;
    unsigned short* ef = s_ef[wv];
    unsigned short* h1 = s_h1[wv];

    float w3t[4], b2t[4];
#pragma unroll
    for (int q = 0; q < 4; ++q) { w3t[q] = w3[16 * q + m]; b2t[q] = b2[16 * q + m]; }
    float b3 = b3v[0];

    {   // zero-pad ef k=80..95 once
        int r = lane >> 2, c0 = (lane & 3) * 4;
#pragma unroll
        for (int q = 0; q < 4; ++q) ef[r * EF_STRIDE + 80 + c0 + q] = 0;
    }

    int ntiles = (E + 15) >> 4;
    int gw = blockIdx.x * 4 + wv;
    int nw = gridDim.x * 4;

    for (int tile = gw; tile < ntiles; tile += nw) {
        int e0 = tile << 4;
        int e = e0 + m;
        bool ok = (e < E);
        int si = ok ? srcA[e] : 0;
        int di = ok ? dstA[e] : 0;
#pragma unroll
        for (int q = 0; q < 5; ++q) {
            int f = 20 * g + 4 * q;
            ushort4 v; v.x = 0; v.y = 0; v.z = 0; v.w = 0;
            if (ok) {
                if (f < 32)       v = *(const ushort4*)(z16 + (size_t)si * 32 + f);
                else if (f < 64)  v = *(const ushort4*)(z16 + (size_t)di * 32 + (f - 32));
                else              v = *(const ushort4*)(ea16 + (size_t)e * 16 + (f - 64));
            }
            *(ushort4*)&ef[m * EF_STRIDE + f] = v;
        }
        asm volatile("s_waitcnt lgkmcnt(0)" ::: "memory");
        __builtin_amdgcn_sched_barrier(0);

        f32x4 acc1[8] = {};
#pragma unroll
        for (int c = 0; c < 3; ++c) {
            half8 a = *(half8*)&ef[m * EF_STRIDE + 32 * c + 8 * g];
#pragma unroll
            for (int tt = 0; tt < 8; ++tt) {
                half8 w = *(const half8*)&s_pw[(c * 8 + tt) * 512 + lane * 8];
                acc1[tt] = __builtin_amdgcn_mfma_f32_16x16x32_f16(a, w, acc1[tt], 0, 0, 0);
            }
        }
#pragma unroll
        for (int tt = 0; tt < 8; ++tt) {
            int col = 16 * tt + m;
            float cb = s_c1[col], cg = s_c1[128 + col], cb2 = s_c1[256 + col];
#pragma unroll
            for (int r = 0; r < 4; ++r) {
                float v = fmaxf(acc1[tt][r] + cb, 0.f) * cg + cb2;
                h1[(4 * g + r) * H1_STRIDE + col] = f2h(v);
            }
        }
        asm volatile("s_waitcnt lgkmcnt(0)" ::: "memory");
        __builtin_amdgcn_sched_barrier(0);

        f32x4 acc2[4] = {};
#pragma unroll
        for (int c = 0; c < 4; ++c) {
            half8 a = *(half8*)&h1[m * H1_STRIDE + 32 * c + 8 * g];
#pragma unroll
            for (int tt = 0; tt < 4; ++tt) {
                half8 w = *(const half8*)&s_pw[(24 + c * 4 + tt) * 512 + lane * 8];
                acc2[tt] = __builtin_amdgcn_mfma_f32_16x16x32_f16(a, w, acc2[tt], 0, 0, 0);
            }
        }
        float s[4];
#pragma unroll
        for (int r = 0; r < 4; ++r) {
            float acc = 0.f;
#pragma unroll
            for (int tt = 0; tt < 4; ++tt) {
                float v = fmaxf(acc2[tt][r] + b2t[tt], 0.f);
                acc = fmaf(v, w3t[tt], acc);
            }
            acc += __shfl_xor(acc, 1);
            acc += __shfl_xor(acc, 2);
            acc += __shfl_xor(acc, 4);
            acc += __shfl_xor(acc, 8);
            s[r] = acc;
        }
        if (m == 0) {
            int eb = e0 + 4 * g;
            if (eb + 3 < E) {
                float4 o;
                o.x = 1.f / (1.f + expf(-(s[0] + b3)));
                o.y = 1.f / (1.f + expf(-(s[1] + b3)));
                o.z = 1.f / (1.f + expf(-(s[2] + b3)));
                o.w = 1.f / (1.f + expf(-(s[3] + b3)));
                *(float4*)(out + eb) = o;
            } else {
#pragma unroll
                for (int r = 0; r < 4; ++r)
                    if (eb + r < E) out[eb + r] = 1.f / (1.f + expf(-(s[r] + b3)));
            }
        }
    }
}

// =====================================================================================
extern "C" void kernel_launch(void* const* d_in, const int* in_sizes, int n_in,
                              void* d_out, int out_size, void* d_ws, size_t ws_size,
                              hipStream_t stream)
{
    const float* x    = (const float*)d_in[0];
    const float* ea   = (const float*)d_in[1];
    const float* W0   = (const float*)d_in[2];
    const float* We0  = (const float*)d_in[3];
    const float* as0  = (const float*)d_in[4];
    const float* ad0  = (const float*)d_in[5];
    const float* ae0  = (const float*)d_in[6];
    const float* b0   = (const float*)d_in[7];
    const float* bn0g = (const float*)d_in[8];
    const float* bn0b = (const float*)d_in[9];
    const float* W1   = (const float*)d_in[10];
    const float* We1  = (const float*)d_in[11];
    const float* as1  = (const float*)d_in[12];
    const float* ad1  = (const float*)d_in[13];
    const float* ae1  = (const float*)d_in[14];
    const float* b1   = (const float*)d_in[15];
    const float* ndW1 = (const float*)d_in[16];
    const float* ndb1 = (const float*)d_in[17];
    const float* ndg  = (const float*)d_in[18];
    const float* ndbb = (const float*)d_in[19];
    const float* ndW2 = (const float*)d_in[20];
    const float* ndb2 = (const float*)d_in[21];
    const float* ndW3 = (const float*)d_in[22];
    const float* ndb3 = (const float*)d_in[23];
    const float* edW1 = (const float*)d_in[24];
    const float* edb1 = (const float*)d_in[25];
    const float* edg  = (const float*)d_in[26];
    const float* edbb = (const float*)d_in[27];
    const float* edW2 = (const float*)d_in[28];
    const float* edb2 = (const float*)d_in[29];
    const float* edW3 = (const float*)d_in[30];
    const float* edb3 = (const float*)d_in[31];
    const int*   eidx = (const int*)d_in[32];

    const int N = in_sizes[0] / 128;
    const int E = in_sizes[1] / 16;
    const int* srcA = eidx;
    const int* dstA = eidx + E;

    char* ws = (char*)d_ws;
    size_t o = 0;
    auto alloc = [&](size_t bytes) -> void* {
        void* p = ws + o;
        o = (o + bytes + 255) & ~(size_t)255;
        return p;
    };
    typedef unsigned short u16;
    u16*   x16    = (u16*)alloc((size_t)N * 128 * 2);
    u16*   xw0_16 = (u16*)alloc((size_t)N * 256 * 2);
    u16*   hbuf16 = (u16*)alloc((size_t)N * 256 * 2);
    u16*   xw1_16 = (u16*)alloc((size_t)N * 32 * 2);
    u16*   z16    = (u16*)alloc((size_t)N * 32 * 2);
    u16*   n1_16  = (u16*)alloc((size_t)N * 128 * 2);
    u16*   h2n16  = (u16*)alloc((size_t)N * 64 * 2);
    u16*   ea16   = (u16*)alloc((size_t)E * 16 * 2);
    float* a_s0   = (float*)alloc((size_t)N * 4 * 4);
    float* a_d0   = (float*)alloc((size_t)N * 4 * 4);
    float* a_e0a  = (float*)alloc((size_t)(E + N) * 4 * 4);
    float* a_e1a  = (float*)alloc((size_t)(E + N) * 4);
    float* a_s1   = (float*)alloc((size_t)N * 4);
    float* a_d1   = (float*)alloc((size_t)N * 4);
    float* lattr  = (float*)alloc((size_t)N * 16 * 4);
    int*   deg    = (int*)alloc((size_t)N * 4);
    int*   rowptr = (int*)alloc((size_t)(N + 1) * 4);
    int*   cur    = (int*)alloc((size_t)N * 4);
    int*   col    = (int*)alloc((size_t)(E + N) * 4);
    float* v0     = (float*)alloc(64 * 4);
    float* v1     = (float*)alloc(16 * 4);
    u16*   pw     = (u16*)alloc((size_t)160 * 512 * 2);

    float* z_out    = (float*)d_out;
    float* node_out = z_out + (size_t)N * 32;
    float* edge_out = node_out + (size_t)N * 128;

    // weights / constants / CSR
    k_pack_all<<<160, 512, 0, stream>>>(W0, W1, ndW1, ndW2, ndW3, edW1, edW2, pw);
    k_ae_vec<<<1, 128, 0, stream>>>(We0, ae0, We1, ae1, v0, v1);
    k_cvt<<<((long)N * 128 / 4 + 255) / 256, 256, 0, stream>>>(x, x16, (long)N * 128);
    k_deg_init<<<(N + 255) / 256, 256, 0, stream>>>(deg, N);
    k_deg_count<<<(E + 255) / 256, 256, 0, stream>>>(dstA, deg, E);
    k_scan<<<1, 1024, 0, stream>>>(deg, rowptr, cur, N);
    k_fill<<<(E + N + 255) / 256, 256, 0, stream>>>(dstA, cur, col, E, N);
    k_loop_mean<<<(N + 3) / 4, 256, 0, stream>>>(rowptr, col, ea, lattr, N, E);
    k_edge_ae<<<(E + N + 255) / 256, 256, 0, stream>>>(ea, lattr, v0, v1, a_e0a, a_e1a, ea16, E, N);

    // GAT layer 0
    k_gemm16<4, 16, 0><<<782, 256, 0, stream>>>(x16, pw + 0 * 512, xw0_16, N, nullptr, nullptr, nullptr);
    k_attdots0<<<(N + 3) / 4, 256, 0, stream>>>(xw0_16, as0, ad0, a_s0, a_d0, N);
    k_gat0_agg<<<N, 64, 0, stream>>>(rowptr, col, srcA, a_s0, a_d0, a_e0a, xw0_16, b0, bn0g, bn0b,
                                     hbuf16, N, E);

    // GAT layer 1
    k_gemm16<8, 2, 0><<<782, 256, 0, stream>>>(hbuf16, pw + (size_t)64 * 512, xw1_16, N, nullptr, nullptr, nullptr);
    k_attdots1<<<(N + 255) / 256, 256, 0, stream>>>(xw1_16, as1, ad1, a_s1, a_d1, N);
    k_gat1_agg<<<N, 64, 0, stream>>>(rowptr, col, srcA, a_s1, a_d1, a_e1a, xw1_16, b1,
                                     z_out, z16, N, E);

    // node decoder
    k_gemm16<1, 8, 2><<<782, 256, 0, stream>>>(z16, pw + (size_t)80 * 512, n1_16, N, ndb1, ndg, ndbb);
    k_gemm16<4, 4, 1><<<782, 256, 0, stream>>>(n1_16, pw + (size_t)88 * 512, h2n16, N, ndb2, nullptr, nullptr);
    k_gemm16<2, 8, 3><<<782, 256, 0, stream>>>(h2n16, pw + (size_t)104 * 512, node_out, N, ndb3, nullptr, nullptr);

    // edge decoder
    k_edge_dec_mfma<<<1024, 256, 0, stream>>>(z16, ea16, srcA, dstA, pw + (size_t)120 * 512,
                                              edb1, edb2, edW3, edb3, edg, edbb, edge_out, E);
}

// Round 4
// 531.737 us; speedup vs baseline: 2.7321x; 1.2100x over previous
//
#include <hip/hip_runtime.h>
#include <math.h>

#define BN_K 0.9999950000374997f  // 1/sqrt(1+1e-5)

static __device__ __forceinline__ float lrelu02(float x) { return x > 0.f ? x : 0.2f * x; }

typedef _Float16 half8 __attribute__((ext_vector_type(8)));
typedef float f32x4 __attribute__((ext_vector_type(4)));

static __device__ __forceinline__ unsigned short f2h(float x)
{
    union { _Float16 h; unsigned short u; } q;
    q.h = (_Float16)x;
    return q.u;
}
static __device__ __forceinline__ float h2f(unsigned short u)
{
    union { unsigned short u; _Float16 h; } q;
    q.u = u;
    return (float)q.h;
}

// ---------------- tiny precompute: v0[4][16] = We0[:,h*64:+64] @ ae0[h]; v1[16] = We1 @ ae1 ----
__global__ void k_ae_vec(const float* __restrict__ We0, const float* __restrict__ ae0,
                         const float* __restrict__ We1, const float* __restrict__ ae1,
                         float* __restrict__ v0, float* __restrict__ v1)
{
    int t = threadIdx.x;
    if (t < 64) {
        int h = t >> 4, k = t & 15;
        float s = 0.f;
        for (int c = 0; c < 64; ++c) s += We0[k * 256 + h * 64 + c] * ae0[h * 64 + c];
        v0[h * 16 + k] = s;
    } else if (t < 80) {
        int k = t - 64;
        float s = 0.f;
        for (int c = 0; c < 32; ++c) s += We1[k * 32 + c] * ae1[c];
        v1[k] = s;
    }
}

// ---------------- fp32 -> f16 convert ----------------
__global__ void k_cvt(const float* __restrict__ in, unsigned short* __restrict__ out, long n)
{
    long i = ((long)blockIdx.x * blockDim.x + threadIdx.x) * 4;
    if (i + 3 < n) {
        float4 v = *(const float4*)(in + i);
        ushort4 o;
        o.x = f2h(v.x); o.y = f2h(v.y); o.z = f2h(v.z); o.w = f2h(v.w);
        *(ushort4*)(out + i) = o;
    } else {
        for (; i < n; ++i) out[i] = f2h(in[i]);
    }
}

// ---------------- CSR build over dst (self-loops included: deg init = 1) ----------------
__global__ void k_deg_init(int* __restrict__ deg, int N)
{
    int i = blockIdx.x * blockDim.x + threadIdx.x;
    if (i < N) deg[i] = 1;
}

__global__ void k_deg_count(const int* __restrict__ dst, int* __restrict__ deg, int E)
{
    int e = blockIdx.x * blockDim.x + threadIdx.x;
    if (e < E) atomicAdd(&deg[dst[e]], 1);
}

// ---------------- 2-level scan (replaces single-block serial scan) ----------------
#define SCHUNK 4096
__global__ __launch_bounds__(1024) void k_scan1(const int* __restrict__ deg,
                                                int* __restrict__ rowptr,
                                                int* __restrict__ bsum, int n)
{
    __shared__ int sbuf[1024];
    int b = blockIdx.x, t = threadIdx.x;
    int i0 = b * SCHUNK + t * 4;
    int v[4];
#pragma unroll
    for (int j = 0; j < 4; ++j) v[j] = (i0 + j < n) ? deg[i0 + j] : 0;
    int s = v[0] + v[1] + v[2] + v[3];
    sbuf[t] = s;
    __syncthreads();
    for (int d = 1; d < 1024; d <<= 1) {
        int tmp = (t >= d) ? sbuf[t - d] : 0;
        __syncthreads();
        sbuf[t] += tmp;
        __syncthreads();
    }
    int run = sbuf[t] - s;
#pragma unroll
    for (int j = 0; j < 4; ++j) {
        run += v[j];
        if (i0 + j < n) rowptr[i0 + j + 1] = run;  // chunk-local inclusive
    }
    if (t == 1023) bsum[b] = sbuf[1023];
}

__global__ void k_scan2(const int* __restrict__ bsum, int* __restrict__ boffs,
                        int nb, int* __restrict__ rowptr)
{
    if (threadIdx.x == 0) {
        int acc = 0;
        for (int b = 0; b < nb; ++b) { boffs[b] = acc; acc += bsum[b]; }
        rowptr[0] = 0;
    }
}

__global__ void k_scan3(const int* __restrict__ boffs, const int* __restrict__ deg,
                        int* __restrict__ rowptr, int* __restrict__ cur, int n)
{
    int i = blockIdx.x * blockDim.x + threadIdx.x;
    if (i >= n) return;
    int r = rowptr[i + 1] + boffs[i / SCHUNK];
    rowptr[i + 1] = r;
    cur[i] = r - deg[i];
}

__global__ void k_fill(const int* __restrict__ dst, int* __restrict__ cur,
                       int* __restrict__ col, int E, int N)
{
    int t = blockIdx.x * blockDim.x + threadIdx.x;
    if (t >= E + N) return;
    int d = (t < E) ? dst[t] : (t - E);
    int slot = atomicAdd(&cur[d], 1);
    col[slot] = t;  // eid: t<E original edge; t=E+i self-loop of node i
}

// ---------------- self-loop edge_attr = scatter-mean via CSR ----------------
__global__ __launch_bounds__(256) void k_loop_mean(
    const int* __restrict__ rowptr, const int* __restrict__ col,
    const float* __restrict__ ea, float* __restrict__ loop_attr, int N, int E)
{
    int wv = threadIdx.x >> 6, lane = threadIdx.x & 63;
    int i = blockIdx.x * 4 + wv;
    if (i >= N) return;
    int beg = rowptr[i], end = rowptr[i + 1];
    int q = lane >> 4, k = lane & 15;
    float sum = 0.f;
    for (int p = beg + q; p < end; p += 4) {
        int eid = col[p];
        if (eid < E) sum += ea[(size_t)eid * 16 + k];
    }
    sum += __shfl_xor(sum, 16);
    sum += __shfl_xor(sum, 32);
    if (lane < 16) {
        int cnt = end - beg - 1;  // exactly one self-loop per node
        loop_attr[(size_t)i * 16 + k] = sum / (float)max(cnt, 1);
    }
}

// ---------------- per-edge attention-edge terms + ea16 emit ----------------
__global__ void k_edge_ae(const float* __restrict__ ea, const float* __restrict__ loop_attr,
                          const float* __restrict__ v0, const float* __restrict__ v1,
                          float* __restrict__ a_e0, float* __restrict__ a_e1,
                          unsigned short* __restrict__ ea16, int E, int N)
{
    int idx = blockIdx.x * blockDim.x + threadIdx.x;
    if (idx >= E + N) return;
    const float* row = (idx < E) ? (ea + (size_t)idx * 16) : (loop_attr + (size_t)(idx - E) * 16);
    float r[16];
#pragma unroll
    for (int k = 0; k < 16; ++k) r[k] = row[k];
#pragma unroll
    for (int h = 0; h < 4; ++h) {
        float s = 0.f;
#pragma unroll
        for (int k = 0; k < 16; ++k) s = fmaf(r[k], v0[h * 16 + k], s);
        a_e0[(size_t)idx * 4 + h] = s;
    }
    float s1 = 0.f;
#pragma unroll
    for (int k = 0; k < 16; ++k) s1 = fmaf(r[k], v1[k], s1);
    a_e1[idx] = s1;
    if (idx < E) {
#pragma unroll
        for (int k = 0; k < 16; k += 4) {
            ushort4 o;
            o.x = f2h(r[k]); o.y = f2h(r[k + 1]); o.z = f2h(r[k + 2]); o.w = f2h(r[k + 3]);
            *(ushort4*)(ea16 + (size_t)idx * 16 + k) = o;
        }
    }
}

// ---------------- pack ALL weights into f16 MFMA fragments ----------------
// sigma(g,i)=8g+i; element (frag f, lane l, i) = W[k=32c+8g+i][n=16t+m], 0 if k>=K.
// frag ranges: [0,64) W0(128,256) c*16+t | [64,80) W1(256,32) c*2+t | [80,88) ndW1(32,128) t
// [88,104) ndW2(128,64) c*4+t | [104,120) ndW3(64,128) c*8+t | [120,144) edW1(80->96,128) c*8+t
// [144,160) edW2(128,64) c*4+t
__global__ __launch_bounds__(512) void k_pack_all(
    const float* __restrict__ W0, const float* __restrict__ W1,
    const float* __restrict__ nd1, const float* __restrict__ nd2, const float* __restrict__ nd3,
    const float* __restrict__ ed1, const float* __restrict__ ed2,
    unsigned short* __restrict__ pw)
{
    int f = blockIdx.x, t = threadIdx.x;
    int l = t >> 3, i = t & 7, g = l >> 4, m = l & 15;
    const float* W; int K, Nn, c, tt;
    if (f < 64)       { W = W0;  K = 128; Nn = 256; int q = f;       c = q >> 4; tt = q & 15; }
    else if (f < 80)  { W = W1;  K = 256; Nn = 32;  int q = f - 64;  c = q >> 1; tt = q & 1;  }
    else if (f < 88)  { W = nd1; K = 32;  Nn = 128; int q = f - 80;  c = 0;      tt = q;      }
    else if (f < 104) { W = nd2; K = 128; Nn = 64;  int q = f - 88;  c = q >> 2; tt = q & 3;  }
    else if (f < 120) { W = nd3; K = 64;  Nn = 128; int q = f - 104; c = q >> 3; tt = q & 7;  }
    else if (f < 144) { W = ed1; K = 80;  Nn = 128; int q = f - 120; c = q >> 3; tt = q & 7;  }
    else              { W = ed2; K = 128; Nn = 64;  int q = f - 144; c = q >> 2; tt = q & 3;  }
    int k = 32 * c + 8 * g + i, n = 16 * tt + m;
    float v = (k < K) ? W[(size_t)k * Nn + n] : 0.f;
    pw[(size_t)f * 512 + t] = f2h(v);
}

// ---------------- generic f16 MFMA GEMM: out = A16[M,K] @ B(frags) with epilogue ----------------
// MODE 0: raw -> f16 ; 1: relu(+bias) -> f16 ; 2: BN(relu(+bias)) -> f16 ; 3: +bias -> fp32
template <int KC, int NT, int MODE>
__global__ __launch_bounds__(256) void k_gemm16(
    const unsigned short* __restrict__ A16, const unsigned short* __restrict__ pwB,
    void* __restrict__ outp, int M,
    const float* __restrict__ bias, const float* __restrict__ g_,
    const float* __restrict__ bb_)
{
    constexpr int K = KC * 32;
    constexpr int LDA = K + 8;
    __shared__ unsigned short s_pw[KC * NT * 512];
    __shared__ unsigned short s_a[64 * LDA];
    __shared__ float s_c[3 * NT * 16];

    int t = threadIdx.x;
    for (int idx = t; idx < KC * NT * 64; idx += 256)
        *(half8*)&s_pw[idx * 8] = *(const half8*)&pwB[idx * 8];
    if (MODE) {
        for (int c = t; c < NT * 16; c += 256) {
            s_c[c] = bias[c];
            if (MODE == 2) { s_c[NT * 16 + c] = g_[c] * BN_K; s_c[2 * NT * 16 + c] = bb_[c]; }
        }
    }
    int wv = t >> 6, lane = t & 63, gq = lane >> 4, m = lane & 15;
    int nrt = (M + 63) >> 6;
    for (int rt = blockIdx.x; rt < nrt; rt += gridDim.x) {
        int r0 = rt << 6;
        __syncthreads();
        for (int idx = t; idx < 64 * (K / 8); idx += 256) {
            int row = idx / (K / 8), cb = idx % (K / 8);
            half8 v = {};
            if (r0 + row < M) v = *(const half8*)&A16[(size_t)(r0 + row) * K + cb * 8];
            *(half8*)&s_a[row * LDA + cb * 8] = v;
        }
        __syncthreads();
        f32x4 acc[NT] = {};
#pragma unroll
        for (int c = 0; c < KC; ++c) {
            half8 a = *(half8*)&s_a[(wv * 16 + m) * LDA + 32 * c + 8 * gq];
#pragma unroll
            for (int tt = 0; tt < NT; ++tt) {
                half8 b = *(const half8*)&s_pw[(c * NT + tt) * 512 + lane * 8];
                acc[tt] = __builtin_amdgcn_mfma_f32_16x16x32_f16(a, b, acc[tt], 0, 0, 0);
            }
        }
#pragma unroll
        for (int tt = 0; tt < NT; ++tt) {
            int col = 16 * tt + m;
            float cb = MODE ? s_c[col] : 0.f;
#pragma unroll
            for (int r = 0; r < 4; ++r) {
                int row = r0 + wv * 16 + 4 * gq + r;
                float v = acc[tt][r] + cb;
                if (MODE == 1) v = fmaxf(v, 0.f);
                if (MODE == 2) v = fmaxf(v, 0.f) * s_c[NT * 16 + col] + s_c[2 * NT * 16 + col];
                if (MODE == 3) {
                    if (row < M) ((float*)outp)[(size_t)row * (NT * 16) + col] = v;
                } else {
                    float o = __shfl_xor(v, 1);
                    if (!(m & 1) && row < M) {
                        unsigned int u = (unsigned)f2h(v) | ((unsigned)f2h(o) << 16);
                        *(unsigned int*)&((unsigned short*)outp)[(size_t)row * (NT * 16) + col] = u;
                    }
                }
            }
        }
    }
}

// ---------------- attention source/dest dots, layer 0 (wave per node, f16 xw) ----------------
__global__ void k_attdots0(const unsigned short* __restrict__ xw16, const float* __restrict__ as0,
                           const float* __restrict__ ad0, float* __restrict__ a_s,
                           float* __restrict__ a_d, int N)
{
    int wid = (blockIdx.x * blockDim.x + threadIdx.x) >> 6;
    int lane = threadIdx.x & 63;
    if (wid >= N) return;
    int h = lane >> 4, c4 = (lane & 15) * 4;
    ushort4 xv4 = *(const ushort4*)(xw16 + (size_t)wid * 256 + lane * 4);
    float4 sv = *(const float4*)(as0 + h * 64 + c4);
    float4 dv = *(const float4*)(ad0 + h * 64 + c4);
    float x0 = h2f(xv4.x), x1 = h2f(xv4.y), x2 = h2f(xv4.z), x3 = h2f(xv4.w);
    float ps = x0 * sv.x + x1 * sv.y + x2 * sv.z + x3 * sv.w;
    float pd = x0 * dv.x + x1 * dv.y + x2 * dv.z + x3 * dv.w;
#pragma unroll
    for (int mm = 1; mm < 16; mm <<= 1) { ps += __shfl_xor(ps, mm); pd += __shfl_xor(pd, mm); }
    if ((lane & 15) == 0) { a_s[(size_t)wid * 4 + h] = ps; a_d[(size_t)wid * 4 + h] = pd; }
}

__global__ void k_attdots1(const unsigned short* __restrict__ xw16, const float* __restrict__ as1,
                           const float* __restrict__ ad1, float* __restrict__ a_s,
                           float* __restrict__ a_d, int N)
{
    int i = blockIdx.x * blockDim.x + threadIdx.x;
    if (i >= N) return;
    float s = 0.f, d = 0.f;
    for (int j0 = 0; j0 < 32; j0 += 4) {
        ushort4 v4 = *(const ushort4*)(xw16 + (size_t)i * 32 + j0);
        float v[4] = {h2f(v4.x), h2f(v4.y), h2f(v4.z), h2f(v4.w)};
#pragma unroll
        for (int j = 0; j < 4; ++j) {
            s = fmaf(v[j], as1[j0 + j], s);
            d = fmaf(v[j], ad1[j0 + j], d);
        }
    }
    a_s[i] = s; a_d[i] = d;
}

// ---------------- GAT layer 0 aggregation: wave per node, f16 gather, fused BN/ELU ------------
__global__ __launch_bounds__(64) void k_gat0_agg(
    const int* __restrict__ rowptr, const int* __restrict__ col, const int* __restrict__ srcA,
    const float* __restrict__ a_s, const float* __restrict__ a_d, const float* __restrict__ a_e,
    const unsigned short* __restrict__ xw16, const float* __restrict__ b0,
    const float* __restrict__ bng, const float* __restrict__ bnb,
    unsigned short* __restrict__ hout16, int N, int E)
{
    int i = blockIdx.x;
    int lane = threadIdx.x;
    int beg = rowptr[i], end = rowptr[i + 1];
    float ad[4];
#pragma unroll
    for (int h = 0; h < 4; ++h) ad[h] = a_d[(size_t)i * 4 + h];

    float mx[4] = {-1e30f, -1e30f, -1e30f, -1e30f};
    for (int p = beg + lane; p < end; p += 64) {
        int eid = col[p];
        int s = (eid < E) ? srcA[eid] : i;
        float4 as4 = *(const float4*)(a_s + (size_t)s * 4);
        float4 ae4 = *(const float4*)(a_e + (size_t)eid * 4);
        mx[0] = fmaxf(mx[0], lrelu02(as4.x + ad[0] + ae4.x));
        mx[1] = fmaxf(mx[1], lrelu02(as4.y + ad[1] + ae4.y));
        mx[2] = fmaxf(mx[2], lrelu02(as4.z + ad[2] + ae4.z));
        mx[3] = fmaxf(mx[3], lrelu02(as4.w + ad[3] + ae4.w));
    }
#pragma unroll
    for (int h = 0; h < 4; ++h)
#pragma unroll
        for (int m = 1; m < 64; m <<= 1) mx[h] = fmaxf(mx[h], __shfl_xor(mx[h], m));

    __shared__ float wls[256];
    int hl = lane >> 4;
    float accx = 0.f, accy = 0.f, accz = 0.f, accw = 0.f;
    float s0 = 0.f, s1 = 0.f, s2 = 0.f, s3 = 0.f;
    for (int base = beg; base < end; base += 64) {
        int p = base + lane;
        int cnt = min(64, end - base);
        if (p < end) {
            int eid = col[p];
            int s = (eid < E) ? srcA[eid] : i;
            float4 as4 = *(const float4*)(a_s + (size_t)s * 4);
            float4 ae4 = *(const float4*)(a_e + (size_t)eid * 4);
            float w0 = expf(lrelu02(as4.x + ad[0] + ae4.x) - mx[0]);
            float w1 = expf(lrelu02(as4.y + ad[1] + ae4.y) - mx[1]);
            float w2 = expf(lrelu02(as4.z + ad[2] + ae4.z) - mx[2]);
            float w3 = expf(lrelu02(as4.w + ad[3] + ae4.w) - mx[3]);
            s0 += w0; s1 += w1; s2 += w2; s3 += w3;
            wls[lane * 4 + 0] = w0; wls[lane * 4 + 1] = w1;
            wls[lane * 4 + 2] = w2; wls[lane * 4 + 3] = w3;
        }
        __syncthreads();
        for (int q = 0; q < cnt; ++q) {
            int eid = col[base + q];
            int s = (eid < E) ? srcA[eid] : i;
            float w = wls[q * 4 + hl];
            ushort4 xv = *(const ushort4*)(xw16 + (size_t)s * 256 + lane * 4);
            accx = fmaf(w, h2f(xv.x), accx);
            accy = fmaf(w, h2f(xv.y), accy);
            accz = fmaf(w, h2f(xv.z), accz);
            accw = fmaf(w, h2f(xv.w), accw);
        }
        __syncthreads();
    }
#pragma unroll
    for (int m = 1; m < 64; m <<= 1) {
        s0 += __shfl_xor(s0, m); s1 += __shfl_xor(s1, m);
        s2 += __shfl_xor(s2, m); s3 += __shfl_xor(s3, m);
    }
    float sden = ((hl == 0) ? s0 : (hl == 1) ? s1 : (hl == 2) ? s2 : s3) + 1e-16f;

    int ch = lane * 4;
    float out[4] = {accx / sden, accy / sden, accz / sden, accw / sden};
    ushort4 ov;
    unsigned short* po = (unsigned short*)&ov;
#pragma unroll
    for (int j = 0; j < 4; ++j) {
        int c = ch + j;
        float v = out[j] + b0[c];
        v = v * (BN_K * bng[c]) + bnb[c];
        po[j] = f2h((v > 0.f) ? v : expm1f(v));
    }
    *(ushort4*)(hout16 + (size_t)i * 256 + ch) = ov;
}

// ---------------- GAT layer 1 aggregation: f16 gather (full-wave), writes z + z16 -------------
__global__ __launch_bounds__(64) void k_gat1_agg(
    const int* __restrict__ rowptr, const int* __restrict__ col, const int* __restrict__ srcA,
    const float* __restrict__ a_s, const float* __restrict__ a_d, const float* __restrict__ a_e,
    const unsigned short* __restrict__ xw16, const float* __restrict__ b1,
    float* __restrict__ zout, unsigned short* __restrict__ z16, int N, int E)
{
    int i = blockIdx.x;
    int lane = threadIdx.x;
    int beg = rowptr[i], end = rowptr[i + 1];
    float ad = a_d[i];
    float mx = -1e30f;
    for (int p = beg + lane; p < end; p += 64) {
        int eid = col[p];
        int s = (eid < E) ? srcA[eid] : i;
        mx = fmaxf(mx, lrelu02(a_s[s] + ad + a_e[eid]));
    }
#pragma unroll
    for (int m = 1; m < 64; m <<= 1) mx = fmaxf(mx, __shfl_xor(mx, m));

    __shared__ float wls[64];
    float acc = 0.f, ssum = 0.f;
    int parity = lane >> 5, j = lane & 31;
    for (int base = beg; base < end; base += 64) {
        int p = base + lane;
        int cnt = min(64, end - base);
        if (p < end) {
            int eid = col[p];
            int s = (eid < E) ? srcA[eid] : i;
            float w = expf(lrelu02(a_s[s] + ad + a_e[eid]) - mx);
            ssum += w;
            wls[lane] = w;
        }
        __syncthreads();
        for (int q = parity; q < cnt; q += 2) {
            int eid = col[base + q];
            int s = (eid < E) ? srcA[eid] : i;
            acc = fmaf(wls[q], h2f(xw16[(size_t)s * 32 + j]), acc);
        }
        __syncthreads();
    }
#pragma unroll
    for (int m = 1; m < 64; m <<= 1) ssum += __shfl_xor(ssum, m);
    acc += __shfl_xor(acc, 32);
    if (lane < 32) {
        float v = acc / (ssum + 1e-16f) + b1[lane];
        zout[(size_t)i * 32 + lane] = v;
        z16[(size_t)i * 32 + lane] = f2h(v);
    }
}

// ---------------- MFMA edge decoder v2: direct fragment gather, w2 in VGPRs ----------------
#define H1_STRIDE 136

__global__ __launch_bounds__(256, 3) void k_edge_dec_mfma(
    const unsigned short* __restrict__ z16, const unsigned short* __restrict__ ea16,
    const int* __restrict__ srcA, const int* __restrict__ dstA,
    const unsigned short* __restrict__ pw,  // pre-offset: frags [0,24)=edW1, [24,40)=edW2
    const float* __restrict__ b1, const float* __restrict__ b2,
    const float* __restrict__ w3, const float* __restrict__ b3v,
    const float* __restrict__ g1, const float* __restrict__ bb1,
    float* __restrict__ out, int E)
{
    __shared__ unsigned short s_pw[24 * 512];
    __shared__ float s_c1[3 * 128];
    __shared__ unsigned short s_h1[4][16 * H1_STRIDE];

    int t = threadIdx.x;
    for (int idx = t; idx < 1536; idx += 256)
        *(half8*)&s_pw[idx * 8] = *(const half8*)&pw[idx * 8];
    if (t < 128) {
        s_c1[t] = b1[t];
        s_c1[128 + t] = g1[t] * BN_K;
        s_c1[256 + t] = bb1[t];
    }
    __syncthreads();

    int wv = t >> 6, lane = t & 63;
    int g = lane >> 4, m = lane & 15;
    unsigned short* h1 = s_h1[wv];

    // layer-2 weights resident in VGPRs (16 frags x half8 = 64 VGPRs)
    half8 w2r[16];
#pragma unroll
    for (int q = 0; q < 16; ++q)
        w2r[q] = *(const half8*)&pw[(size_t)(24 + q) * 512 + lane * 8];

    float w3t[4], b2t[4];
#pragma unroll
    for (int q = 0; q < 4; ++q) { w3t[q] = w3[16 * q + m]; b2t[q] = b2[16 * q + m]; }
    float b3 = b3v[0];

    int ntiles = (E + 15) >> 4;
    int gw = blockIdx.x * 4 + wv;
    int nw = gridDim.x * 4;

    for (int tile = gw; tile < ntiles; tile += nw) {
        int e0 = tile << 4;
        int e = e0 + m;
        bool ok = (e < E);
        // direct per-lane A-fragment gather: lane (g,m) = edge e0+m, k-slice 8g..8g+7 per chunk
        half8 a0 = {}, a1 = {}, a2 = {};
        if (ok) {
            int si = srcA[e], di = dstA[e];
            a0 = *(const half8*)&z16[(size_t)si * 32 + 8 * g];
            a1 = *(const half8*)&z16[(size_t)di * 32 + 8 * g];
            if (g < 2) a2 = *(const half8*)&ea16[(size_t)e * 16 + 8 * g];
        }

        // ---- layer 1: [16,96] x [96,128]
        f32x4 acc1[8] = {};
#pragma unroll
        for (int tt = 0; tt < 8; ++tt)
            acc1[tt] = __builtin_amdgcn_mfma_f32_16x16x32_f16(a0, *(const half8*)&s_pw[(0 * 8 + tt) * 512 + lane * 8], acc1[tt], 0, 0, 0);
#pragma unroll
        for (int tt = 0; tt < 8; ++tt)
            acc1[tt] = __builtin_amdgcn_mfma_f32_16x16x32_f16(a1, *(const half8*)&s_pw[(1 * 8 + tt) * 512 + lane * 8], acc1[tt], 0, 0, 0);
#pragma unroll
        for (int tt = 0; tt < 8; ++tt)
            acc1[tt] = __builtin_amdgcn_mfma_f32_16x16x32_f16(a2, *(const half8*)&s_pw[(2 * 8 + tt) * 512 + lane * 8], acc1[tt], 0, 0, 0);

        // epilogue: BN(relu(+b1)) -> f16, packed u32 writes (pair lanes m, m^1)
#pragma unroll
        for (int tt = 0; tt < 8; ++tt) {
            int col = 16 * tt + m;
            float cb = s_c1[col], cg = s_c1[128 + col], cb2 = s_c1[256 + col];
#pragma unroll
            for (int r = 0; r < 4; ++r) {
                float v = fmaxf(acc1[tt][r] + cb, 0.f) * cg + cb2;
                float vo = __shfl_xor(v, 1);
                if (!(m & 1)) {
                    unsigned u = (unsigned)f2h(v) | ((unsigned)f2h(vo) << 16);
                    *(unsigned*)&h1[(4 * g + r) * H1_STRIDE + col] = u;
                }
            }
        }
        asm volatile("s_waitcnt lgkmcnt(0)" ::: "memory");
        __builtin_amdgcn_sched_barrier(0);

        // ---- layer 2: [16,128] x [128,64]
        f32x4 acc2[4] = {};
#pragma unroll
        for (int c = 0; c < 4; ++c) {
            half8 a = *(half8*)&h1[m * H1_STRIDE + 32 * c + 8 * g];
#pragma unroll
            for (int tt = 0; tt < 4; ++tt)
                acc2[tt] = __builtin_amdgcn_mfma_f32_16x16x32_f16(a, w2r[c * 4 + tt], acc2[tt], 0, 0, 0);
        }
        // ---- layer 3: relu(+b2) dot w3, 16-lane reduce, sigmoid
        float s[4];
#pragma unroll
        for (int r = 0; r < 4; ++r) {
            float acc = 0.f;
#pragma unroll
            for (int tt = 0; tt < 4; ++tt) {
                float v = fmaxf(acc2[tt][r] + b2t[tt], 0.f);
                acc = fmaf(v, w3t[tt], acc);
            }
            acc += __shfl_xor(acc, 1);
            acc += __shfl_xor(acc, 2);
            acc += __shfl_xor(acc, 4);
            acc += __shfl_xor(acc, 8);
            s[r] = acc;
        }
        if (m == 0) {
            int eb = e0 + 4 * g;
            if (eb + 3 < E) {
                float4 o;
                o.x = 1.f / (1.f + expf(-(s[0] + b3)));
                o.y = 1.f / (1.f + expf(-(s[1] + b3)));
                o.z = 1.f / (1.f + expf(-(s[2] + b3)));
                o.w = 1.f / (1.f + expf(-(s[3] + b3)));
                *(float4*)(out + eb) = o;
            } else {
#pragma unroll
                for (int r = 0; r < 4; ++r)
                    if (eb + r < E) out[eb + r] = 1.f / (1.f + expf(-(s[r] + b3)));
            }
        }
    }
}

// =====================================================================================
extern "C" void kernel_launch(void* const* d_in, const int* in_sizes, int n_in,
                              void* d_out, int out_size, void* d_ws, size_t ws_size,
                              hipStream_t stream)
{
    const float* x    = (const float*)d_in[0];
    const float* ea   = (const float*)d_in[1];
    const float* W0   = (const float*)d_in[2];
    const float* We0  = (const float*)d_in[3];
    const float* as0  = (const float*)d_in[4];
    const float* ad0  = (const float*)d_in[5];
    const float* ae0  = (const float*)d_in[6];
    const float* b0   = (const float*)d_in[7];
    const float* bn0g = (const float*)d_in[8];
    const float* bn0b = (const float*)d_in[9];
    const float* W1   = (const float*)d_in[10];
    const float* We1  = (const float*)d_in[11];
    const float* as1  = (const float*)d_in[12];
    const float* ad1  = (const float*)d_in[13];
    const float* ae1  = (const float*)d_in[14];
    const float* b1   = (const float*)d_in[15];
    const float* ndW1 = (const float*)d_in[16];
    const float* ndb1 = (const float*)d_in[17];
    const float* ndg  = (const float*)d_in[18];
    const float* ndbb = (const float*)d_in[19];
    const float* ndW2 = (const float*)d_in[20];
    const float* ndb2 = (const float*)d_in[21];
    const float* ndW3 = (const float*)d_in[22];
    const float* ndb3 = (const float*)d_in[23];
    const float* edW1 = (const float*)d_in[24];
    const float* edb1 = (const float*)d_in[25];
    const float* edg  = (const float*)d_in[26];
    const float* edbb = (const float*)d_in[27];
    const float* edW2 = (const float*)d_in[28];
    const float* edb2 = (const float*)d_in[29];
    const float* edW3 = (const float*)d_in[30];
    const float* edb3 = (const float*)d_in[31];
    const int*   eidx = (const int*)d_in[32];

    const int N = in_sizes[0] / 128;
    const int E = in_sizes[1] / 16;
    const int* srcA = eidx;
    const int* dstA = eidx + E;

    char* ws = (char*)d_ws;
    size_t o = 0;
    auto alloc = [&](size_t bytes) -> void* {
        void* p = ws + o;
        o = (o + bytes + 255) & ~(size_t)255;
        return p;
    };
    typedef unsigned short u16;
    u16*   x16    = (u16*)alloc((size_t)N * 128 * 2);
    u16*   xw0_16 = (u16*)alloc((size_t)N * 256 * 2);
    u16*   hbuf16 = (u16*)alloc((size_t)N * 256 * 2);
    u16*   xw1_16 = (u16*)alloc((size_t)N * 32 * 2);
    u16*   z16    = (u16*)alloc((size_t)N * 32 * 2);
    u16*   n1_16  = (u16*)alloc((size_t)N * 128 * 2);
    u16*   h2n16  = (u16*)alloc((size_t)N * 64 * 2);
    u16*   ea16   = (u16*)alloc((size_t)E * 16 * 2);
    float* a_s0   = (float*)alloc((size_t)N * 4 * 4);
    float* a_d0   = (float*)alloc((size_t)N * 4 * 4);
    float* a_e0a  = (float*)alloc((size_t)(E + N) * 4 * 4);
    float* a_e1a  = (float*)alloc((size_t)(E + N) * 4);
    float* a_s1   = (float*)alloc((size_t)N * 4);
    float* a_d1   = (float*)alloc((size_t)N * 4);
    float* lattr  = (float*)alloc((size_t)N * 16 * 4);
    int*   deg    = (int*)alloc((size_t)N * 4);
    int*   rowptr = (int*)alloc((size_t)(N + 1) * 4);
    int*   cur    = (int*)alloc((size_t)N * 4);
    int*   col    = (int*)alloc((size_t)(E + N) * 4);
    int*   bsum   = (int*)alloc(64 * 4);
    int*   boffs  = (int*)alloc(64 * 4);
    float* v0     = (float*)alloc(64 * 4);
    float* v1     = (float*)alloc(16 * 4);
    u16*   pw     = (u16*)alloc((size_t)160 * 512 * 2);

    float* z_out    = (float*)d_out;
    float* node_out = z_out + (size_t)N * 32;
    float* edge_out = node_out + (size_t)N * 128;

    const int nb = (N + SCHUNK - 1) / SCHUNK;

    // weights / constants / CSR
    k_pack_all<<<160, 512, 0, stream>>>(W0, W1, ndW1, ndW2, ndW3, edW1, edW2, pw);
    k_ae_vec<<<1, 128, 0, stream>>>(We0, ae0, We1, ae1, v0, v1);
    k_cvt<<<((long)N * 128 / 4 + 255) / 256, 256, 0, stream>>>(x, x16, (long)N * 128);
    k_deg_init<<<(N + 255) / 256, 256, 0, stream>>>(deg, N);
    k_deg_count<<<(E + 255) / 256, 256, 0, stream>>>(dstA, deg, E);
    k_scan1<<<nb, 1024, 0, stream>>>(deg, rowptr, bsum, N);
    k_scan2<<<1, 64, 0, stream>>>(bsum, boffs, nb, rowptr);
    k_scan3<<<(N + 255) / 256, 256, 0, stream>>>(boffs, deg, rowptr, cur, N);
    k_fill<<<(E + N + 255) / 256, 256, 0, stream>>>(dstA, cur, col, E, N);
    k_loop_mean<<<(N + 3) / 4, 256, 0, stream>>>(rowptr, col, ea, lattr, N, E);
    k_edge_ae<<<(E + N + 255) / 256, 256, 0, stream>>>(ea, lattr, v0, v1, a_e0a, a_e1a, ea16, E, N);

    // GAT layer 0
    k_gemm16<4, 16, 0><<<782, 256, 0, stream>>>(x16, pw + 0 * 512, xw0_16, N, nullptr, nullptr, nullptr);
    k_attdots0<<<(N + 3) / 4, 256, 0, stream>>>(xw0_16, as0, ad0, a_s0, a_d0, N);
    k_gat0_agg<<<N, 64, 0, stream>>>(rowptr, col, srcA, a_s0, a_d0, a_e0a, xw0_16, b0, bn0g, bn0b,
                                     hbuf16, N, E);

    // GAT layer 1
    k_gemm16<8, 2, 0><<<782, 256, 0, stream>>>(hbuf16, pw + (size_t)64 * 512, xw1_16, N, nullptr, nullptr, nullptr);
    k_attdots1<<<(N + 255) / 256, 256, 0, stream>>>(xw1_16, as1, ad1, a_s1, a_d1, N);
    k_gat1_agg<<<N, 64, 0, stream>>>(rowptr, col, srcA, a_s1, a_d1, a_e1a, xw1_16, b1,
                                     z_out, z16, N, E);

    // node decoder
    k_gemm16<1, 8, 2><<<782, 256, 0, stream>>>(z16, pw + (size_t)80 * 512, n1_16, N, ndb1, ndg, ndbb);
    k_gemm16<4, 4, 1><<<782, 256, 0, stream>>>(n1_16, pw + (size_t)88 * 512, h2n16, N, ndb2, nullptr, nullptr);
    k_gemm16<2, 8, 3><<<782, 256, 0, stream>>>(h2n16, pw + (size_t)104 * 512, node_out, N, ndb3, nullptr, nullptr);

    // edge decoder
    k_edge_dec_mfma<<<1024, 256, 0, stream>>>(z16, ea16, srcA, dstA, pw + (size_t)120 * 512,
                                              edb1, edb2, edW3, edb3, edg, edbb, edge_out, E);
}

// Round 6
// 503.895 us; speedup vs baseline: 2.8830x; 1.0553x over previous
//
#include <hip/hip_runtime.h>
#include <math.h>

#define BN_K 0.9999950000374997f  // 1/sqrt(1+1e-5)

static __device__ __forceinline__ float lrelu02(float x) { return x > 0.f ? x : 0.2f * x; }

typedef _Float16 half8 __attribute__((ext_vector_type(8)));
typedef __fp16 fp16x2 __attribute__((ext_vector_type(2)));
typedef float f32x4 __attribute__((ext_vector_type(4)));

static __device__ __forceinline__ unsigned short f2h(float x)
{
    union { _Float16 h; unsigned short u; } q;
    q.h = (_Float16)x;
    return q.u;
}
static __device__ __forceinline__ float h2f(unsigned short u)
{
    union { unsigned short u; _Float16 h; } q;
    q.u = u;
    return (float)q.h;
}
static __device__ __forceinline__ unsigned pkrtz(float a, float b)
{
    union { fp16x2 h; unsigned u; } q;
    q.h = __builtin_amdgcn_cvt_pkrtz(a, b);
    return q.u;
}

// ---- tiny precompute: v0, v1 attention-edge vectors; b2p = edb2 + edbb @ edW2 ----
__global__ void k_ae_vec(const float* __restrict__ We0, const float* __restrict__ ae0,
                         const float* __restrict__ We1, const float* __restrict__ ae1,
                         const float* __restrict__ edbb, const float* __restrict__ edW2,
                         const float* __restrict__ edb2,
                         float* __restrict__ v0, float* __restrict__ v1,
                         float* __restrict__ b2p)
{
    int t = threadIdx.x;
    if (t < 64) {
        int h = t >> 4, k = t & 15;
        float s = 0.f;
        for (int c = 0; c < 64; ++c) s += We0[k * 256 + h * 64 + c] * ae0[h * 64 + c];
        v0[h * 16 + k] = s;
    } else if (t < 80) {
        int k = t - 64;
        float s = 0.f;
        for (int c = 0; c < 32; ++c) s += We1[k * 32 + c] * ae1[c];
        v1[k] = s;
    } else if (t < 144) {
        int n = t - 80;
        float s = 0.f;
        for (int k = 0; k < 128; ++k) s += edbb[k] * edW2[k * 64 + n];
        b2p[n] = edb2[n] + s;
    }
}

// ---------------- CSR build over dst (self-loops included: deg init = 1) ----------------
__global__ void k_deg_init(int* __restrict__ deg, int N)
{
    int i = blockIdx.x * blockDim.x + threadIdx.x;
    if (i < N) deg[i] = 1;
}

__global__ void k_deg_count(const int* __restrict__ dst, int* __restrict__ deg, int E)
{
    int e = blockIdx.x * blockDim.x + threadIdx.x;
    if (e < E) atomicAdd(&deg[dst[e]], 1);
}

#define SCHUNK 4096
__global__ __launch_bounds__(1024) void k_scan1(const int* __restrict__ deg,
                                                int* __restrict__ rowptr,
                                                int* __restrict__ bsum, int n)
{
    __shared__ int sbuf[1024];
    int b = blockIdx.x, t = threadIdx.x;
    int i0 = b * SCHUNK + t * 4;
    int v[4];
#pragma unroll
    for (int j = 0; j < 4; ++j) v[j] = (i0 + j < n) ? deg[i0 + j] : 0;
    int s = v[0] + v[1] + v[2] + v[3];
    sbuf[t] = s;
    __syncthreads();
    for (int d = 1; d < 1024; d <<= 1) {
        int tmp = (t >= d) ? sbuf[t - d] : 0;
        __syncthreads();
        sbuf[t] += tmp;
        __syncthreads();
    }
    int run = sbuf[t] - s;
#pragma unroll
    for (int j = 0; j < 4; ++j) {
        run += v[j];
        if (i0 + j < n) rowptr[i0 + j + 1] = run;  // chunk-local inclusive
    }
    if (t == 1023) bsum[b] = sbuf[1023];
    if (b == 0 && t == 0) rowptr[0] = 0;
}

__global__ void k_scan3(const int* __restrict__ bsum, const int* __restrict__ deg,
                        int* __restrict__ rowptr, int* __restrict__ cur, int n)
{
    int i = blockIdx.x * blockDim.x + threadIdx.x;
    if (i >= n) return;
    int chunk = i / SCHUNK;
    int off = 0;
    for (int b = 0; b < chunk; ++b) off += bsum[b];
    int r = rowptr[i + 1] + off;
    rowptr[i + 1] = r;
    cur[i] = r - deg[i];
}

__global__ void k_fill(const int* __restrict__ dst, int* __restrict__ cur,
                       int* __restrict__ col, int E, int N)
{
    int t = blockIdx.x * blockDim.x + threadIdx.x;
    if (t >= E + N) return;
    int d = (t < E) ? dst[t] : (t - E);
    int slot = atomicAdd(&cur[d], 1);
    col[slot] = t;  // eid: t<E original edge; t=E+i self-loop of node i
}

// ---------------- self-loop edge_attr = scatter-mean via CSR ----------------
__global__ __launch_bounds__(256) void k_loop_mean(
    const int* __restrict__ rowptr, const int* __restrict__ col,
    const float* __restrict__ ea, float* __restrict__ loop_attr, int N, int E)
{
    int wv = threadIdx.x >> 6, lane = threadIdx.x & 63;
    int i = blockIdx.x * 4 + wv;
    if (i >= N) return;
    int beg = rowptr[i], end = rowptr[i + 1];
    int q = lane >> 4, k = lane & 15;
    float sum = 0.f;
    for (int p = beg + q; p < end; p += 4) {
        int eid = col[p];
        if (eid < E) sum += ea[(size_t)eid * 16 + k];
    }
    sum += __shfl_xor(sum, 16);
    sum += __shfl_xor(sum, 32);
    if (lane < 16) {
        int cnt = end - beg - 1;  // exactly one self-loop per node
        loop_attr[(size_t)i * 16 + k] = sum / (float)max(cnt, 1);
    }
}

// ---------------- per-edge attention-edge terms + ea16 emit ----------------
__global__ void k_edge_ae(const float* __restrict__ ea, const float* __restrict__ loop_attr,
                          const float* __restrict__ v0, const float* __restrict__ v1,
                          float* __restrict__ a_e0, float* __restrict__ a_e1,
                          unsigned short* __restrict__ ea16, int E, int N)
{
    int idx = blockIdx.x * blockDim.x + threadIdx.x;
    if (idx >= E + N) return;
    const float* row = (idx < E) ? (ea + (size_t)idx * 16) : (loop_attr + (size_t)(idx - E) * 16);
    float r[16];
#pragma unroll
    for (int k = 0; k < 16; ++k) r[k] = row[k];
#pragma unroll
    for (int h = 0; h < 4; ++h) {
        float s = 0.f;
#pragma unroll
        for (int k = 0; k < 16; ++k) s = fmaf(r[k], v0[h * 16 + k], s);
        a_e0[(size_t)idx * 4 + h] = s;
    }
    float s1 = 0.f;
#pragma unroll
    for (int k = 0; k < 16; ++k) s1 = fmaf(r[k], v1[k], s1);
    a_e1[idx] = s1;
    if (idx < E) {
#pragma unroll
        for (int k = 0; k < 16; k += 4) {
            ushort4 o;
            o.x = f2h(r[k]); o.y = f2h(r[k + 1]); o.z = f2h(r[k + 2]); o.w = f2h(r[k + 3]);
            *(ushort4*)(ea16 + (size_t)idx * 16 + k) = o;
        }
    }
}

// ---------------- pack ALL weights into f16 MFMA fragments ----------------
// sigma(g,i)=8g+i; element (frag f, lane l, i) = W[k=32c+8g+i][n=16t+m], 0 if k>=K.
// frag ranges: [0,64) W0(128,256) c*16+t | [64,80) W1(256,32) c*2+t | [80,88) ndW1(32,128) t
// [88,104) ndW2(128,64) c*4+t | [104,120) ndW3(64,128) c*8+t
// [120,144) edW1(80,128) + bias row at k=80 | [144,160) edW2(128,64) rows scaled by g1*BN_K
__global__ __launch_bounds__(512) void k_pack_all(
    const float* __restrict__ W0, const float* __restrict__ W1,
    const float* __restrict__ nd1, const float* __restrict__ nd2, const float* __restrict__ nd3,
    const float* __restrict__ ed1, const float* __restrict__ ed2,
    const float* __restrict__ edb1, const float* __restrict__ edg,
    unsigned short* __restrict__ pw)
{
    int f = blockIdx.x, t = threadIdx.x;
    int l = t >> 3, i = t & 7, g = l >> 4, m = l & 15;
    float v;
    if (f < 64) {
        int q = f; int k = 32 * (q >> 4) + 8 * g + i, n = 16 * (q & 15) + m;
        v = W0[(size_t)k * 256 + n];
    } else if (f < 80) {
        int q = f - 64; int k = 32 * (q >> 1) + 8 * g + i, n = 16 * (q & 1) + m;
        v = W1[(size_t)k * 32 + n];
    } else if (f < 88) {
        int q = f - 80; int k = 8 * g + i, n = 16 * q + m;
        v = nd1[(size_t)k * 128 + n];
    } else if (f < 104) {
        int q = f - 88; int k = 32 * (q >> 2) + 8 * g + i, n = 16 * (q & 3) + m;
        v = nd2[(size_t)k * 64 + n];
    } else if (f < 120) {
        int q = f - 104; int k = 32 * (q >> 3) + 8 * g + i, n = 16 * (q & 7) + m;
        v = nd3[(size_t)k * 128 + n];
    } else if (f < 144) {
        int q = f - 120; int k = 32 * (q >> 3) + 8 * g + i, n = 16 * (q & 7) + m;
        v = (k < 80) ? ed1[(size_t)k * 128 + n] : (k == 80 ? edb1[n] : 0.f);
    } else {
        int q = f - 144; int k = 32 * (q >> 2) + 8 * g + i, n = 16 * (q & 3) + m;
        v = ed2[(size_t)k * 64 + n] * (edg[k] * BN_K);
    }
    pw[(size_t)f * 512 + t] = f2h(v);
}

// ---------------- generic f16 MFMA GEMM with epilogue ----------------
// MODE 0: raw -> f16 ; 1: relu(+bias) -> f16 ; 2: BN(relu(+bias)) -> f16 ; 3: +bias -> fp32
// AF32: A input is fp32, converted during staging. NTOT: total n-tiles in pw (col split).
template <int KC, int NT, int MODE, int AF32, int NTOT>
__global__ __launch_bounds__(256) void k_gemm16(
    const void* __restrict__ Ain, const unsigned short* __restrict__ pwB,
    void* __restrict__ outp, int M,
    const float* __restrict__ bias, const float* __restrict__ g_,
    const float* __restrict__ bb_)
{
    constexpr int K = KC * 32;
    constexpr int LDA = K + 8;
    __shared__ unsigned short s_pw[KC * NT * 512];
    __shared__ unsigned short s_a[64 * LDA];
    __shared__ float s_c[3 * NT * 16];

    int t = threadIdx.x;
    int ttoff = blockIdx.y * NT;
    for (int idx = t; idx < KC * NT * 64; idx += 256) {
        int f = idx >> 6, e8 = idx & 63;
        int c = f / NT, tt = f - c * NT;
        *(half8*)&s_pw[(size_t)idx * 8] =
            *(const half8*)&pwB[(((size_t)(c * NTOT + ttoff + tt)) * 64 + e8) * 8];
    }
    if (MODE) {
        for (int c = t; c < NT * 16; c += 256) {
            s_c[c] = bias[ttoff * 16 + c];
            if (MODE == 2) {
                s_c[NT * 16 + c] = g_[ttoff * 16 + c] * BN_K;
                s_c[2 * NT * 16 + c] = bb_[ttoff * 16 + c];
            }
        }
    }
    int wv = t >> 6, lane = t & 63, gq = lane >> 4, m = lane & 15;
    int nrt = (M + 63) >> 6;
    for (int rt = blockIdx.x; rt < nrt; rt += gridDim.x) {
        int r0 = rt << 6;
        __syncthreads();
        for (int idx = t; idx < 64 * (K / 8); idx += 256) {
            int row = idx / (K / 8), cb = idx % (K / 8);
            half8 v = {};
            if (r0 + row < M) {
                if (AF32) {
                    const float* Af = (const float*)Ain + (size_t)(r0 + row) * K + cb * 8;
                    float4 u0 = *(const float4*)Af;
                    float4 u1 = *(const float4*)(Af + 4);
                    union { half8 h; unsigned u[4]; } q;
                    q.u[0] = pkrtz(u0.x, u0.y); q.u[1] = pkrtz(u0.z, u0.w);
                    q.u[2] = pkrtz(u1.x, u1.y); q.u[3] = pkrtz(u1.z, u1.w);
                    v = q.h;
                } else {
                    v = *(const half8*)&((const unsigned short*)Ain)[(size_t)(r0 + row) * K + cb * 8];
                }
            }
            *(half8*)&s_a[row * LDA + cb * 8] = v;
        }
        __syncthreads();
        f32x4 acc[NT] = {};
#pragma unroll
        for (int c = 0; c < KC; ++c) {
            half8 a = *(half8*)&s_a[(wv * 16 + m) * LDA + 32 * c + 8 * gq];
#pragma unroll
            for (int tt = 0; tt < NT; ++tt) {
                half8 b = *(const half8*)&s_pw[(c * NT + tt) * 512 + lane * 8];
                acc[tt] = __builtin_amdgcn_mfma_f32_16x16x32_f16(a, b, acc[tt], 0, 0, 0);
            }
        }
#pragma unroll
        for (int tt = 0; tt < NT; ++tt) {
            int col = 16 * tt + m;
            int ocol = ttoff * 16 + col;
            float cb = MODE ? s_c[col] : 0.f;
#pragma unroll
            for (int r = 0; r < 4; ++r) {
                int row = r0 + wv * 16 + 4 * gq + r;
                float v = acc[tt][r] + cb;
                if (MODE == 1) v = fmaxf(v, 0.f);
                if (MODE == 2) v = fmaxf(v, 0.f) * s_c[NT * 16 + col] + s_c[2 * NT * 16 + col];
                if (MODE == 3) {
                    if (row < M) ((float*)outp)[(size_t)row * (NTOT * 16) + ocol] = v;
                } else {
                    float o = __shfl_xor(v, 1);
                    if (!(m & 1) && row < M)
                        *(unsigned*)&((unsigned short*)outp)[(size_t)row * (NTOT * 16) + ocol] =
                            pkrtz(v, o);
                }
            }
        }
    }
}

// ---------------- attention source/dest dots ----------------
__global__ void k_attdots0(const unsigned short* __restrict__ xw16, const float* __restrict__ as0,
                           const float* __restrict__ ad0, float* __restrict__ a_s,
                           float* __restrict__ a_d, int N)
{
    int wid = (blockIdx.x * blockDim.x + threadIdx.x) >> 6;
    int lane = threadIdx.x & 63;
    if (wid >= N) return;
    int h = lane >> 4, c4 = (lane & 15) * 4;
    ushort4 xv4 = *(const ushort4*)(xw16 + (size_t)wid * 256 + lane * 4);
    float4 sv = *(const float4*)(as0 + h * 64 + c4);
    float4 dv = *(const float4*)(ad0 + h * 64 + c4);
    float x0 = h2f(xv4.x), x1 = h2f(xv4.y), x2 = h2f(xv4.z), x3 = h2f(xv4.w);
    float ps = x0 * sv.x + x1 * sv.y + x2 * sv.z + x3 * sv.w;
    float pd = x0 * dv.x + x1 * dv.y + x2 * dv.z + x3 * dv.w;
#pragma unroll
    for (int mm = 1; mm < 16; mm <<= 1) { ps += __shfl_xor(ps, mm); pd += __shfl_xor(pd, mm); }
    if ((lane & 15) == 0) { a_s[(size_t)wid * 4 + h] = ps; a_d[(size_t)wid * 4 + h] = pd; }
}

__global__ void k_attdots1(const unsigned short* __restrict__ xw16, const float* __restrict__ as1,
                           const float* __restrict__ ad1, float* __restrict__ a_s,
                           float* __restrict__ a_d, int N)
{
    int i = blockIdx.x * blockDim.x + threadIdx.x;
    if (i >= N) return;
    float s = 0.f, d = 0.f;
    for (int j0 = 0; j0 < 32; j0 += 4) {
        ushort4 v4 = *(const ushort4*)(xw16 + (size_t)i * 32 + j0);
        float v[4] = {h2f(v4.x), h2f(v4.y), h2f(v4.z), h2f(v4.w)};
#pragma unroll
        for (int j = 0; j < 4; ++j) {
            s = fmaf(v[j], as1[j0 + j], s);
            d = fmaf(v[j], ad1[j0 + j], d);
        }
    }
    a_s[i] = s; a_d[i] = d;
}

// ---------------- GAT layer 0 aggregation: wave per node, alpha cached for first 64 edges ----
__global__ __launch_bounds__(64) void k_gat0_agg(
    const int* __restrict__ rowptr, const int* __restrict__ col, const int* __restrict__ srcA,
    const float* __restrict__ a_s, const float* __restrict__ a_d, const float* __restrict__ a_e,
    const unsigned short* __restrict__ xw16, const float* __restrict__ b0,
    const float* __restrict__ bng, const float* __restrict__ bnb,
    unsigned short* __restrict__ hout16, int N, int E)
{
    int i = blockIdx.x;
    int lane = threadIdx.x;
    int beg = rowptr[i], end = rowptr[i + 1];
    float ad[4];
#pragma unroll
    for (int h = 0; h < 4; ++h) ad[h] = a_d[(size_t)i * 4 + h];

    // pass 1: alpha for p0 = beg+lane cached in al[]; rest folded into max only
    float al[4] = {-1e30f, -1e30f, -1e30f, -1e30f};
    int p0 = beg + lane;
    if (p0 < end) {
        int eid = col[p0];
        int s = (eid < E) ? srcA[eid] : i;
        float4 as4 = *(const float4*)(a_s + (size_t)s * 4);
        float4 ae4 = *(const float4*)(a_e + (size_t)eid * 4);
        al[0] = lrelu02(as4.x + ad[0] + ae4.x);
        al[1] = lrelu02(as4.y + ad[1] + ae4.y);
        al[2] = lrelu02(as4.z + ad[2] + ae4.z);
        al[3] = lrelu02(as4.w + ad[3] + ae4.w);
    }
    float mx[4] = {al[0], al[1], al[2], al[3]};
    for (int p = p0 + 64; p < end; p += 64) {
        int eid = col[p];
        int s = (eid < E) ? srcA[eid] : i;
        float4 as4 = *(const float4*)(a_s + (size_t)s * 4);
        float4 ae4 = *(const float4*)(a_e + (size_t)eid * 4);
        mx[0] = fmaxf(mx[0], lrelu02(as4.x + ad[0] + ae4.x));
        mx[1] = fmaxf(mx[1], lrelu02(as4.y + ad[1] + ae4.y));
        mx[2] = fmaxf(mx[2], lrelu02(as4.z + ad[2] + ae4.z));
        mx[3] = fmaxf(mx[3], lrelu02(as4.w + ad[3] + ae4.w));
    }
#pragma unroll
    for (int h = 0; h < 4; ++h)
#pragma unroll
        for (int m = 1; m < 64; m <<= 1) mx[h] = fmaxf(mx[h], __shfl_xor(mx[h], m));

    __shared__ float wls[256];
    int hl = lane >> 4;
    float accx = 0.f, accy = 0.f, accz = 0.f, accw = 0.f;
    float s0 = 0.f, s1 = 0.f, s2 = 0.f, s3 = 0.f;
    for (int base = beg; base < end; base += 64) {
        int p = base + lane;
        int cnt = min(64, end - base);
        if (p < end) {
            float aa0, aa1, aa2, aa3;
            if (base == beg) { aa0 = al[0]; aa1 = al[1]; aa2 = al[2]; aa3 = al[3]; }
            else {
                int eid = col[p];
                int s = (eid < E) ? srcA[eid] : i;
                float4 as4 = *(const float4*)(a_s + (size_t)s * 4);
                float4 ae4 = *(const float4*)(a_e + (size_t)eid * 4);
                aa0 = lrelu02(as4.x + ad[0] + ae4.x);
                aa1 = lrelu02(as4.y + ad[1] + ae4.y);
                aa2 = lrelu02(as4.z + ad[2] + ae4.z);
                aa3 = lrelu02(as4.w + ad[3] + ae4.w);
            }
            float w0 = expf(aa0 - mx[0]);
            float w1 = expf(aa1 - mx[1]);
            float w2 = expf(aa2 - mx[2]);
            float w3 = expf(aa3 - mx[3]);
            s0 += w0; s1 += w1; s2 += w2; s3 += w3;
            wls[lane * 4 + 0] = w0; wls[lane * 4 + 1] = w1;
            wls[lane * 4 + 2] = w2; wls[lane * 4 + 3] = w3;
        }
        __syncthreads();
        for (int q = 0; q < cnt; ++q) {
            int eid = col[base + q];
            int s = (eid < E) ? srcA[eid] : i;
            float w = wls[q * 4 + hl];
            ushort4 xv = *(const ushort4*)(xw16 + (size_t)s * 256 + lane * 4);
            accx = fmaf(w, h2f(xv.x), accx);
            accy = fmaf(w, h2f(xv.y), accy);
            accz = fmaf(w, h2f(xv.z), accz);
            accw = fmaf(w, h2f(xv.w), accw);
        }
        __syncthreads();
    }
#pragma unroll
    for (int m = 1; m < 64; m <<= 1) {
        s0 += __shfl_xor(s0, m); s1 += __shfl_xor(s1, m);
        s2 += __shfl_xor(s2, m); s3 += __shfl_xor(s3, m);
    }
    float sden = ((hl == 0) ? s0 : (hl == 1) ? s1 : (hl == 2) ? s2 : s3) + 1e-16f;

    int ch = lane * 4;
    float out[4] = {accx / sden, accy / sden, accz / sden, accw / sden};
    ushort4 ov;
    unsigned short* po = (unsigned short*)&ov;
#pragma unroll
    for (int j = 0; j < 4; ++j) {
        int c = ch + j;
        float v = out[j] + b0[c];
        v = v * (BN_K * bng[c]) + bnb[c];
        po[j] = f2h((v > 0.f) ? v : expm1f(v));
    }
    *(ushort4*)(hout16 + (size_t)i * 256 + ch) = ov;
}

// ---------------- GAT layer 1 aggregation: alpha cached, full-wave accumulate ----------------
__global__ __launch_bounds__(64) void k_gat1_agg(
    const int* __restrict__ rowptr, const int* __restrict__ col, const int* __restrict__ srcA,
    const float* __restrict__ a_s, const float* __restrict__ a_d, const float* __restrict__ a_e,
    const unsigned short* __restrict__ xw16, const float* __restrict__ b1,
    float* __restrict__ zout, unsigned short* __restrict__ z16, int N, int E)
{
    int i = blockIdx.x;
    int lane = threadIdx.x;
    int beg = rowptr[i], end = rowptr[i + 1];
    float ad = a_d[i];
    float al = -1e30f;
    int p0 = beg + lane;
    if (p0 < end) {
        int eid = col[p0];
        int s = (eid < E) ? srcA[eid] : i;
        al = lrelu02(a_s[s] + ad + a_e[eid]);
    }
    float mx = al;
    for (int p = p0 + 64; p < end; p += 64) {
        int eid = col[p];
        int s = (eid < E) ? srcA[eid] : i;
        mx = fmaxf(mx, lrelu02(a_s[s] + ad + a_e[eid]));
    }
#pragma unroll
    for (int m = 1; m < 64; m <<= 1) mx = fmaxf(mx, __shfl_xor(mx, m));

    __shared__ float wls[64];
    float acc = 0.f, ssum = 0.f;
    int parity = lane >> 5, j = lane & 31;
    for (int base = beg; base < end; base += 64) {
        int p = base + lane;
        int cnt = min(64, end - base);
        if (p < end) {
            float aa;
            if (base == beg) aa = al;
            else {
                int eid = col[p];
                int s = (eid < E) ? srcA[eid] : i;
                aa = lrelu02(a_s[s] + ad + a_e[eid]);
            }
            float w = expf(aa - mx);
            ssum += w;
            wls[lane] = w;
        }
        __syncthreads();
        for (int q = parity; q < cnt; q += 2) {
            int eid = col[base + q];
            int s = (eid < E) ? srcA[eid] : i;
            acc = fmaf(wls[q], h2f(xw16[(size_t)s * 32 + j]), acc);
        }
        __syncthreads();
    }
#pragma unroll
    for (int m = 1; m < 64; m <<= 1) ssum += __shfl_xor(ssum, m);
    acc += __shfl_xor(acc, 32);
    if (lane < 32) {
        float v = acc / (ssum + 1e-16f) + b1[lane];
        zout[(size_t)i * 32 + lane] = v;
        z16[(size_t)i * 32 + lane] = f2h(v);
    }
}

// ---------------- MFMA edge decoder v3: bias/BN folded, prefetch pipeline ----------------
#define H1_STRIDE 136

__global__ __launch_bounds__(256, 3) void k_edge_dec_mfma(
    const unsigned short* __restrict__ z16, const unsigned short* __restrict__ ea16,
    const int* __restrict__ srcA, const int* __restrict__ dstA,
    const unsigned short* __restrict__ pw,  // [0,24)=edW1+b1row, [24,40)=edW2*gscale
    const float* __restrict__ b2p, const float* __restrict__ w3,
    const float* __restrict__ b3v, float* __restrict__ out, int E)
{
    __shared__ unsigned short s_pw[24 * 512];
    __shared__ unsigned short s_h1[4][16 * H1_STRIDE];

    int t = threadIdx.x;
    for (int idx = t; idx < 1536; idx += 256)
        *(half8*)&s_pw[idx * 8] = *(const half8*)&pw[idx * 8];
    __syncthreads();

    int wv = t >> 6, lane = t & 63;
    int g = lane >> 4, m = lane & 15;
    unsigned short* h1 = s_h1[wv];

    half8 w2r[16];
#pragma unroll
    for (int q = 0; q < 16; ++q)
        w2r[q] = *(const half8*)&pw[(size_t)(24 + q) * 512 + lane * 8];

    float w3t[4], b2t[4];
#pragma unroll
    for (int q = 0; q < 4; ++q) { w3t[q] = w3[16 * q + m]; b2t[q] = b2p[16 * q + m]; }
    float b3 = b3v[0];

    int ntiles = (E + 15) >> 4;
    int gw = blockIdx.x * 4 + wv;
    int nw = gridDim.x * 4;

    // prefetch first tile
    half8 a0n = {}, a1n = {}, a2n = {};
    {
        int e = (gw << 4) + m;
        if (gw < ntiles && e < E) {
            int si = srcA[e], di = dstA[e];
            a0n = *(const half8*)&z16[(size_t)si * 32 + 8 * g];
            a1n = *(const half8*)&z16[(size_t)di * 32 + 8 * g];
            if (g < 2) a2n = *(const half8*)&ea16[(size_t)e * 16 + 8 * g];
        }
        if (g == 2) a2n[0] = (_Float16)1.f;  // k=80 constant -> b1 row of edW1
    }

    for (int tile = gw; tile < ntiles; ) {
        half8 a0 = a0n, a1 = a1n, a2 = a2n;
        int e0 = tile << 4;
        int nxt = tile + nw;

        // prefetch next tile (hides under MFMA)
        a0n = half8{}; a1n = half8{}; a2n = half8{};
        {
            int e = (nxt << 4) + m;
            if (nxt < ntiles && e < E) {
                int si = srcA[e], di = dstA[e];
                a0n = *(const half8*)&z16[(size_t)si * 32 + 8 * g];
                a1n = *(const half8*)&z16[(size_t)di * 32 + 8 * g];
                if (g < 2) a2n = *(const half8*)&ea16[(size_t)e * 16 + 8 * g];
            }
            if (g == 2) a2n[0] = (_Float16)1.f;
        }

        // ---- layer 1: [16,96] x [96,128], bias baked in
        f32x4 acc1[8] = {};
#pragma unroll
        for (int tt = 0; tt < 8; ++tt)
            acc1[tt] = __builtin_amdgcn_mfma_f32_16x16x32_f16(a0, *(const half8*)&s_pw[(0 * 8 + tt) * 512 + lane * 8], acc1[tt], 0, 0, 0);
#pragma unroll
        for (int tt = 0; tt < 8; ++tt)
            acc1[tt] = __builtin_amdgcn_mfma_f32_16x16x32_f16(a1, *(const half8*)&s_pw[(1 * 8 + tt) * 512 + lane * 8], acc1[tt], 0, 0, 0);
#pragma unroll
        for (int tt = 0; tt < 8; ++tt)
            acc1[tt] = __builtin_amdgcn_mfma_f32_16x16x32_f16(a2, *(const half8*)&s_pw[(2 * 8 + tt) * 512 + lane * 8], acc1[tt], 0, 0, 0);

        // epilogue: u = relu(acc1) -> f16 packed u32 writes (BN folded into W2/b2p)
#pragma unroll
        for (int tt = 0; tt < 8; ++tt) {
#pragma unroll
            for (int r = 0; r < 4; ++r) {
                float v = fmaxf(acc1[tt][r], 0.f);
                float vo = __shfl_xor(v, 1);
                if (!(m & 1))
                    *(unsigned*)&h1[(4 * g + r) * H1_STRIDE + 16 * tt + m] = pkrtz(v, vo);
            }
        }
        asm volatile("s_waitcnt lgkmcnt(0)" ::: "memory");
        __builtin_amdgcn_sched_barrier(0);

        // ---- layer 2: [16,128] x [128,64] (W2 pre-scaled by BN gamma)
        f32x4 acc2[4] = {};
#pragma unroll
        for (int c = 0; c < 4; ++c) {
            half8 a = *(half8*)&h1[m * H1_STRIDE + 32 * c + 8 * g];
#pragma unroll
            for (int tt = 0; tt < 4; ++tt)
                acc2[tt] = __builtin_amdgcn_mfma_f32_16x16x32_f16(a, w2r[c * 4 + tt], acc2[tt], 0, 0, 0);
        }
        // ---- layer 3: relu(+b2p) dot w3, 16-lane reduce, sigmoid
        float s[4];
#pragma unroll
        for (int r = 0; r < 4; ++r) {
            float acc = 0.f;
#pragma unroll
            for (int tt = 0; tt < 4; ++tt) {
                float v = fmaxf(acc2[tt][r] + b2t[tt], 0.f);
                acc = fmaf(v, w3t[tt], acc);
            }
            acc += __shfl_xor(acc, 1);
            acc += __shfl_xor(acc, 2);
            acc += __shfl_xor(acc, 4);
            acc += __shfl_xor(acc, 8);
            s[r] = acc;
        }
        if (m == 0) {
            int eb = e0 + 4 * g;
            if (eb + 3 < E) {
                float4 o;
                o.x = 1.f / (1.f + expf(-(s[0] + b3)));
                o.y = 1.f / (1.f + expf(-(s[1] + b3)));
                o.z = 1.f / (1.f + expf(-(s[2] + b3)));
                o.w = 1.f / (1.f + expf(-(s[3] + b3)));
                *(float4*)(out + eb) = o;
            } else {
#pragma unroll
                for (int r = 0; r < 4; ++r)
                    if (eb + r < E) out[eb + r] = 1.f / (1.f + expf(-(s[r] + b3)));
            }
        }
        tile = nxt;
    }
}

// =====================================================================================
extern "C" void kernel_launch(void* const* d_in, const int* in_sizes, int n_in,
                              void* d_out, int out_size, void* d_ws, size_t ws_size,
                              hipStream_t stream)
{
    const float* x    = (const float*)d_in[0];
    const float* ea   = (const float*)d_in[1];
    const float* W0   = (const float*)d_in[2];
    const float* We0  = (const float*)d_in[3];
    const float* as0  = (const float*)d_in[4];
    const float* ad0  = (const float*)d_in[5];
    const float* ae0  = (const float*)d_in[6];
    const float* b0   = (const float*)d_in[7];
    const float* bn0g = (const float*)d_in[8];
    const float* bn0b = (const float*)d_in[9];
    const float* W1   = (const float*)d_in[10];
    const float* We1  = (const float*)d_in[11];
    const float* as1  = (const float*)d_in[12];
    const float* ad1  = (const float*)d_in[13];
    const float* ae1  = (const float*)d_in[14];
    const float* b1   = (const float*)d_in[15];
    const float* ndW1 = (const float*)d_in[16];
    const float* ndb1 = (const float*)d_in[17];
    const float* ndg  = (const float*)d_in[18];
    const float* ndbb = (const float*)d_in[19];
    const float* ndW2 = (const float*)d_in[20];
    const float* ndb2 = (const float*)d_in[21];
    const float* ndW3 = (const float*)d_in[22];
    const float* ndb3 = (const float*)d_in[23];
    const float* edW1 = (const float*)d_in[24];
    const float* edb1 = (const float*)d_in[25];
    const float* edg  = (const float*)d_in[26];
    const float* edbb = (const float*)d_in[27];
    const float* edW2 = (const float*)d_in[28];
    const float* edb2 = (const float*)d_in[29];
    const float* edW3 = (const float*)d_in[30];
    const float* edb3 = (const float*)d_in[31];
    const int*   eidx = (const int*)d_in[32];

    const int N = in_sizes[0] / 128;
    const int E = in_sizes[1] / 16;
    const int* srcA = eidx;
    const int* dstA = eidx + E;

    char* ws = (char*)d_ws;
    size_t o = 0;
    auto alloc = [&](size_t bytes) -> void* {
        void* p = ws + o;
        o = (o + bytes + 255) & ~(size_t)255;
        return p;
    };
    typedef unsigned short u16;
    u16*   xw0_16 = (u16*)alloc((size_t)N * 256 * 2);
    u16*   hbuf16 = (u16*)alloc((size_t)N * 256 * 2);
    u16*   xw1_16 = (u16*)alloc((size_t)N * 32 * 2);
    u16*   z16    = (u16*)alloc((size_t)N * 32 * 2);
    u16*   n1_16  = (u16*)alloc((size_t)N * 128 * 2);
    u16*   h2n16  = (u16*)alloc((size_t)N * 64 * 2);
    u16*   ea16   = (u16*)alloc((size_t)E * 16 * 2);
    float* a_s0   = (float*)alloc((size_t)N * 4 * 4);
    float* a_d0   = (float*)alloc((size_t)N * 4 * 4);
    float* a_e0a  = (float*)alloc((size_t)(E + N) * 4 * 4);
    float* a_e1a  = (float*)alloc((size_t)(E + N) * 4);
    float* a_s1   = (float*)alloc((size_t)N * 4);
    float* a_d1   = (float*)alloc((size_t)N * 4);
    float* lattr  = (float*)alloc((size_t)N * 16 * 4);
    int*   deg    = (int*)alloc((size_t)N * 4);
    int*   rowptr = (int*)alloc((size_t)(N + 1) * 4);
    int*   cur    = (int*)alloc((size_t)N * 4);
    int*   col    = (int*)alloc((size_t)(E + N) * 4);
    int*   bsum   = (int*)alloc(64 * 4);
    float* v0     = (float*)alloc(64 * 4);
    float* v1     = (float*)alloc(16 * 4);
    float* b2p    = (float*)alloc(64 * 4);
    u16*   pw     = (u16*)alloc((size_t)160 * 512 * 2);

    float* z_out    = (float*)d_out;
    float* node_out = z_out + (size_t)N * 32;
    float* edge_out = node_out + (size_t)N * 128;

    const int nb = (N + SCHUNK - 1) / SCHUNK;
    const int nrt = (N + 63) / 64;

    // weights / constants / CSR
    k_pack_all<<<160, 512, 0, stream>>>(W0, W1, ndW1, ndW2, ndW3, edW1, edW2, edb1, edg, pw);
    k_ae_vec<<<1, 192, 0, stream>>>(We0, ae0, We1, ae1, edbb, edW2, edb2, v0, v1, b2p);
    k_deg_init<<<(N + 255) / 256, 256, 0, stream>>>(deg, N);
    k_deg_count<<<(E + 255) / 256, 256, 0, stream>>>(dstA, deg, E);
    k_scan1<<<nb, 1024, 0, stream>>>(deg, rowptr, bsum, N);
    k_scan3<<<(N + 255) / 256, 256, 0, stream>>>(bsum, deg, rowptr, cur, N);
    k_fill<<<(E + N + 255) / 256, 256, 0, stream>>>(dstA, cur, col, E, N);
    k_loop_mean<<<(N + 3) / 4, 256, 0, stream>>>(rowptr, col, ea, lattr, N, E);
    k_edge_ae<<<(E + N + 255) / 256, 256, 0, stream>>>(ea, lattr, v0, v1, a_e0a, a_e1a, ea16, E, N);

    // GAT layer 0 (xw0 GEMM reads fp32 x directly, col-split into 2)
    k_gemm16<4, 8, 0, 1, 16><<<dim3(nrt, 2), 256, 0, stream>>>(x, pw, xw0_16, N, nullptr, nullptr, nullptr);
    k_attdots0<<<(N + 3) / 4, 256, 0, stream>>>(xw0_16, as0, ad0, a_s0, a_d0, N);
    k_gat0_agg<<<N, 64, 0, stream>>>(rowptr, col, srcA, a_s0, a_d0, a_e0a, xw0_16, b0, bn0g, bn0b,
                                     hbuf16, N, E);

    // GAT layer 1
    k_gemm16<8, 2, 0, 0, 2><<<dim3(nrt, 1), 256, 0, stream>>>(hbuf16, pw + (size_t)64 * 512, xw1_16, N, nullptr, nullptr, nullptr);
    k_attdots1<<<(N + 255) / 256, 256, 0, stream>>>(xw1_16, as1, ad1, a_s1, a_d1, N);
    k_gat1_agg<<<N, 64, 0, stream>>>(rowptr, col, srcA, a_s1, a_d1, a_e1a, xw1_16, b1,
                                     z_out, z16, N, E);

    // node decoder
    k_gemm16<1, 8, 2, 0, 8><<<dim3(nrt, 1), 256, 0, stream>>>(z16, pw + (size_t)80 * 512, n1_16, N, ndb1, ndg, ndbb);
    k_gemm16<4, 4, 1, 0, 4><<<dim3(nrt, 1), 256, 0, stream>>>(n1_16, pw + (size_t)88 * 512, h2n16, N, ndb2, nullptr, nullptr);
    k_gemm16<2, 8, 3, 0, 8><<<dim3(nrt, 1), 256, 0, stream>>>(h2n16, pw + (size_t)104 * 512, node_out, N, ndb3, nullptr, nullptr);

    // edge decoder
    k_edge_dec_mfma<<<1024, 256, 0, stream>>>(z16, ea16, srcA, dstA, pw + (size_t)120 * 512,
                                              b2p, edW3, edb3, edge_out, E);
}